// Round 1
// baseline (735.890 us; speedup 1.0000x reference)
//
#include <hip/hip_runtime.h>
#include <math.h>

#define Bn   8
#define Tn   256
#define INn  128
#define Hn   128
#define OUTn 128
#define Ln   2
#define COREn (Hn*Hn + Hn)     /* 16512 */
#define SDn   (Ln*COREn + 1)   /* 33025 */

// ---------------------------------------------------------------- rotate
__global__ __launch_bounds__(64) void rotate_kernel(
    const float* __restrict__ z, const float* __restrict__ state,
    float* __restrict__ x) {
  int bt = blockIdx.x; int b = bt >> 8; int t = bt & 255;
  int j = threadIdx.x;                       // 0..63 (pair index)
  float ts  = state[(size_t)b*SDn + SDn - 1];
  float pos = ts + (float)t;
  float freq = expf((float)(2*j) * (-9.210340371976184f / 128.0f)); // exp(2j*-ln(1e4)/d)
  float ang = pos * freq;
  float s = sinf(ang), c = cosf(ang);
  const float* zr = z + ((size_t)t*Bn + b)*INn;
  float x1 = zr[j], x2 = zr[j + 64];
  float* xr = x + ((size_t)b*Tn + t)*INn;
  xr[j]      = x1*c - x2*s;
  xr[j + 64] = x2*c + x1*s;
}

// ---------------------------------------------------------------- layernorm
__global__ __launch_bounds__(128) void ln_kernel(
    const float* __restrict__ xin, const float* __restrict__ w,
    const float* __restrict__ bvec, float* __restrict__ out) {
  int row = blockIdx.x; int j = threadIdx.x;
  __shared__ float red[128];
  float v = xin[(size_t)row*INn + j];
  red[j] = v; __syncthreads();
  for (int s = 64; s > 0; s >>= 1) { if (j < s) red[j] += red[j+s]; __syncthreads(); }
  float mean = red[0] * (1.0f/INn);
  __syncthreads();
  float d = v - mean;
  red[j] = d*d; __syncthreads();
  for (int s = 64; s > 0; s >>= 1) { if (j < s) red[j] += red[j+s]; __syncthreads(); }
  float var = red[0] * (1.0f/INn);
  out[(size_t)row*INn + j] = d / sqrtf(var + 1e-5f) * w[j] + bvec[j];
}

// ---------------------------------------------------------------- general NT GEMM
// C[m][n] = epi( sum_k A[m*Kd+k] * Bm[n*Kd+k] )   A:(M,Kd) row-major, Bm:(N,Kd) row-major
// mode: 0 none, 1 elu+1, 2 relu, 3 causal-mask (zero where n>m), 4 (T,B) transposed store
__global__ __launch_bounds__(256) void gemm_nt(
    const float* __restrict__ Abase, const float* __restrict__ Bbase,
    float* __restrict__ Cbase, const float* __restrict__ bias,
    const float* __restrict__ addsrc,
    int M, int N, int Kd,
    long long sA, long long sB, long long sC, int mode) {
  int z = blockIdx.z;
  const float* A  = Abase + (size_t)z * sA;
  const float* Bm = Bbase + (size_t)z * sB;
  float*       C  = Cbase + (size_t)z * sC;
  int m0 = blockIdx.x * 64;
  int n0 = blockIdx.y * 128;
  int tid = threadIdx.x, ty = tid >> 4, tx = tid & 15;

  __shared__ float A_lds[64][33];
  __shared__ float B_lds[128][33];
  float acc[4][8] = {};

  for (int kc = 0; kc < Kd; kc += 32) {
    // A tile: 64 rows x 32 k = 512 float4
    for (int f = tid; f < 512; f += 256) {
      int r = f >> 3, kv = f & 7;
      float4 v = *(const float4*)&A[(size_t)(m0 + r)*Kd + kc + kv*4];
      A_lds[r][kv*4+0] = v.x; A_lds[r][kv*4+1] = v.y;
      A_lds[r][kv*4+2] = v.z; A_lds[r][kv*4+3] = v.w;
    }
    // B tile: 128 rows x 32 k = 1024 float4
    for (int f = tid; f < 1024; f += 256) {
      int r = f >> 3, kv = f & 7;
      float4 v = *(const float4*)&Bm[(size_t)(n0 + r)*Kd + kc + kv*4];
      B_lds[r][kv*4+0] = v.x; B_lds[r][kv*4+1] = v.y;
      B_lds[r][kv*4+2] = v.z; B_lds[r][kv*4+3] = v.w;
    }
    __syncthreads();
    for (int kk = 0; kk < 32; ++kk) {
      float a[4], bb[8];
      #pragma unroll
      for (int i = 0; i < 4; i++) a[i] = A_lds[ty*4 + i][kk];
      #pragma unroll
      for (int j = 0; j < 8; j++) bb[j] = B_lds[tx*8 + j][kk];
      #pragma unroll
      for (int i = 0; i < 4; i++)
        #pragma unroll
        for (int j = 0; j < 8; j++)
          acc[i][j] = fmaf(a[i], bb[j], acc[i][j]);
    }
    __syncthreads();
  }

  #pragma unroll
  for (int i = 0; i < 4; i++) {
    int m = m0 + ty*4 + i;
    #pragma unroll
    for (int j = 0; j < 8; j++) {
      int n = n0 + tx*8 + j;
      float v = acc[i][j];
      if (bias) v += bias[n];
      if (mode == 1)      v = (v > 0.f) ? (v + 1.f) : expf(v);   // elu(v)+1
      else if (mode == 2) v = fmaxf(v, 0.f);
      else if (mode == 3) { if (n > m) v = 0.f; }
      if (addsrc) v += addsrc[(size_t)m*N + n];
      size_t off;
      if (mode == 4) {
        int b2 = m >> 8; int tt = m & 255;    // m = b*T + t
        off = (size_t)tt*(Bn*(size_t)N) + (size_t)b2*N + n;
      } else {
        off = (size_t)m*N + n;
      }
      C[off] = v;
    }
  }
}

// ---------------------------------------------------------------- den = rowsum(A) + Q.Z0 + 1e-5
__global__ __launch_bounds__(256) void den_kernel(
    const float* __restrict__ Ab, const float* __restrict__ Qb,
    const float* __restrict__ state, float* __restrict__ den, int layer) {
  int t = blockIdx.x, b = blockIdx.y, tid = threadIdx.x;
  float v = Ab[((size_t)b*Tn + t)*Tn + tid];
  float qz = 0.f;
  if (tid < Hn)
    qz = Qb[((size_t)b*Tn + t)*Hn + tid] *
         state[(size_t)b*SDn + (size_t)layer*COREn + Hn*Hn + tid];
  __shared__ float red[256];
  red[tid] = v + qz; __syncthreads();
  for (int s = 128; s > 0; s >>= 1) { if (tid < s) red[tid] += red[tid+s]; __syncthreads(); }
  if (tid == 0) den[(size_t)b*Tn + t] = red[0] + 1e-5f;
}

// ---------------------------------------------------------------- num = (A@V + Q@S0) / den
__global__ __launch_bounds__(256) void attn_num_kernel(
    const float* __restrict__ Ab, const float* __restrict__ Vb,
    const float* __restrict__ Qb, const float* __restrict__ state,
    const float* __restrict__ den, float* __restrict__ out, int layer) {
  int b = blockIdx.z;
  int m0 = blockIdx.x * 64;
  int tid = threadIdx.x, ty = tid >> 4, tx = tid & 15;
  __shared__ float A_lds[64][33];
  __shared__ float B_lds[32][128];
  float acc[4][8] = {};

  // phase 1: A (k = tau, 256) @ V
  for (int kc = 0; kc < Tn; kc += 32) {
    for (int f = tid; f < 512; f += 256) {
      int r = f >> 3, kv = f & 7;
      float4 v = *(const float4*)&Ab[((size_t)b*Tn + m0 + r)*Tn + kc + kv*4];
      A_lds[r][kv*4+0] = v.x; A_lds[r][kv*4+1] = v.y;
      A_lds[r][kv*4+2] = v.z; A_lds[r][kv*4+3] = v.w;
    }
    for (int f = tid; f < 1024; f += 256) {
      int kk = f >> 5, nv = f & 31;
      *(float4*)&B_lds[kk][nv*4] =
          *(const float4*)&Vb[((size_t)b*Tn + kc + kk)*Hn + nv*4];
    }
    __syncthreads();
    for (int kk = 0; kk < 32; ++kk) {
      float a[4], bb[8];
      #pragma unroll
      for (int i = 0; i < 4; i++) a[i] = A_lds[ty*4 + i][kk];
      #pragma unroll
      for (int j = 0; j < 8; j++) bb[j] = B_lds[kk][tx*8 + j];
      #pragma unroll
      for (int i = 0; i < 4; i++)
        #pragma unroll
        for (int j = 0; j < 8; j++)
          acc[i][j] = fmaf(a[i], bb[j], acc[i][j]);
    }
    __syncthreads();
  }
  // phase 2: Q (k = i, 128) @ S0  (scalar loads: state batch stride 33025 breaks 16B align)
  for (int kc = 0; kc < Hn; kc += 32) {
    for (int f = tid; f < 512; f += 256) {
      int r = f >> 3, kv = f & 7;
      float4 v = *(const float4*)&Qb[((size_t)b*Tn + m0 + r)*Hn + kc + kv*4];
      A_lds[r][kv*4+0] = v.x; A_lds[r][kv*4+1] = v.y;
      A_lds[r][kv*4+2] = v.z; A_lds[r][kv*4+3] = v.w;
    }
    for (int f = tid; f < 4096; f += 256) {
      int kk = f >> 7, n = f & 127;
      B_lds[kk][n] = state[(size_t)b*SDn + (size_t)layer*COREn + (size_t)(kc + kk)*Hn + n];
    }
    __syncthreads();
    for (int kk = 0; kk < 32; ++kk) {
      float a[4], bb[8];
      #pragma unroll
      for (int i = 0; i < 4; i++) a[i] = A_lds[ty*4 + i][kk];
      #pragma unroll
      for (int j = 0; j < 8; j++) bb[j] = B_lds[kk][tx*8 + j];
      #pragma unroll
      for (int i = 0; i < 4; i++)
        #pragma unroll
        for (int j = 0; j < 8; j++)
          acc[i][j] = fmaf(a[i], bb[j], acc[i][j]);
    }
    __syncthreads();
  }

  #pragma unroll
  for (int i = 0; i < 4; i++) {
    int t = m0 + ty*4 + i;
    float d = den[(size_t)b*Tn + t];
    #pragma unroll
    for (int j = 0; j < 8; j++)
      out[((size_t)b*Tn + t)*Hn + tx*8 + j] = acc[i][j] / d;
  }
}

// ---------------------------------------------------------------- S_out = S0 + K^T @ V
__global__ __launch_bounds__(256) void state_S_kernel(
    const float* __restrict__ Kb, const float* __restrict__ Vb,
    const float* __restrict__ state, float* __restrict__ st_out, int layer) {
  int b  = blockIdx.y;
  int i0 = blockIdx.x * 32;
  int tid = threadIdx.x, ty = tid >> 4, tx = tid & 15;
  __shared__ float K_lds[32][33];
  __shared__ float V_lds[32][128];
  float acc[2][8] = {};
  for (int kc = 0; kc < Tn; kc += 32) {
    { // K tile: 32 tau x 32 i
      int kk = tid >> 3, iv = tid & 7;
      float4 v = *(const float4*)&Kb[((size_t)b*Tn + kc + kk)*Hn + i0 + iv*4];
      K_lds[kk][iv*4+0] = v.x; K_lds[kk][iv*4+1] = v.y;
      K_lds[kk][iv*4+2] = v.z; K_lds[kk][iv*4+3] = v.w;
    }
    for (int f = tid; f < 1024; f += 256) {
      int kk = f >> 5, nv = f & 31;
      *(float4*)&V_lds[kk][nv*4] =
          *(const float4*)&Vb[((size_t)b*Tn + kc + kk)*Hn + nv*4];
    }
    __syncthreads();
    for (int kk = 0; kk < 32; ++kk) {
      float a0 = K_lds[kk][ty*2], a1 = K_lds[kk][ty*2 + 1];
      float bb[8];
      #pragma unroll
      for (int j = 0; j < 8; j++) bb[j] = V_lds[kk][tx*8 + j];
      #pragma unroll
      for (int j = 0; j < 8; j++) {
        acc[0][j] = fmaf(a0, bb[j], acc[0][j]);
        acc[1][j] = fmaf(a1, bb[j], acc[1][j]);
      }
    }
    __syncthreads();
  }
  #pragma unroll
  for (int i2 = 0; i2 < 2; i2++) {
    int i = i0 + ty*2 + i2;
    #pragma unroll
    for (int j = 0; j < 8; j++) {
      int n = tx*8 + j;
      size_t off = (size_t)b*SDn + (size_t)layer*COREn + (size_t)i*Hn + n;
      st_out[off] = acc[i2][j] + state[off];
    }
  }
}

// ---------------------------------------------------------------- Z_out = Z0 + colsum(K); ts+T
__global__ __launch_bounds__(128) void state_Z_kernel(
    const float* __restrict__ Kb, const float* __restrict__ state,
    float* __restrict__ st_out, int layer) {
  int b = blockIdx.x, i = threadIdx.x;
  float s = 0.f;
  for (int t = 0; t < Tn; t++) s += Kb[((size_t)b*Tn + t)*Hn + i];
  size_t off = (size_t)b*SDn + (size_t)layer*COREn + Hn*Hn + i;
  st_out[off] = s + state[off];
  if (layer == 0 && i == 0)
    st_out[(size_t)b*SDn + SDn - 1] = state[(size_t)b*SDn + SDn - 1] + (float)Tn;
}

// ================================================================ launch
extern "C" void kernel_launch(void* const* d_in, const int* in_sizes, int n_in,
                              void* d_out, int out_size, void* d_ws, size_t ws_size,
                              hipStream_t stream) {
  const float* z       = (const float*)d_in[0];
  const float* state   = (const float*)d_in[1];
  const float* Wk      = (const float*)d_in[2];
  const float* Wq      = (const float*)d_in[3];
  const float* Wv      = (const float*)d_in[4];
  const float* ln_w    = (const float*)d_in[5];
  const float* ln_b    = (const float*)d_in[6];
  const float* ff_w1   = (const float*)d_in[7];
  const float* ff_b1   = (const float*)d_in[8];
  const float* ff_w2   = (const float*)d_in[9];
  const float* ff_b2   = (const float*)d_in[10];
  const float* sc_w    = (const float*)d_in[11];
  const float* sc_b    = (const float*)d_in[12];
  const float* unmap_w = (const float*)d_in[13];
  const float* unmap_b = (const float*)d_in[14];

  float* y_out  = (float*)d_out;                       // (T,B,OUT)
  float* st_out = y_out + (size_t)Tn*Bn*OUTn;          // (B,SD)

  const size_t XSZ = (size_t)Bn*Tn*Hn;                 // 262144
  float* ws   = (float*)d_ws;
  float* x    = ws;                 // activations (B,T,IN)
  float* xln  = x    + XSZ;
  float* Kb   = xln  + XSZ;
  float* Qb   = Kb   + XSZ;
  float* Vb   = Qb   + XSZ;
  float* Ab   = Vb   + XSZ;         // (B,T,T) = 524288
  float* den  = Ab   + (size_t)Bn*Tn*Tn;  // 2048
  float* attn = den  + 2048;        // (B,T,H)
  float* h1   = attn + XSZ;
  float* tmp2 = h1   + XSZ;

  rotate_kernel<<<Bn*Tn, 64, 0, stream>>>(z, state, x);

  for (int l = 0; l < Ln; l++) {
    ln_kernel<<<Bn*Tn, 128, 0, stream>>>(x, ln_w + (size_t)l*INn, ln_b + (size_t)l*INn, xln);

    // K = elu(xln@Wk^T)+1 ; Q = elu(xln@Wq^T)+1 ; V = xln@Wv^T
    gemm_nt<<<dim3(32,1,1), 256, 0, stream>>>(xln, Wk + (size_t)l*Hn*INn, Kb,
        nullptr, nullptr, Bn*Tn, Hn, INn, 0,0,0, 1);
    gemm_nt<<<dim3(32,1,1), 256, 0, stream>>>(xln, Wq + (size_t)l*Hn*INn, Qb,
        nullptr, nullptr, Bn*Tn, Hn, INn, 0,0,0, 1);
    gemm_nt<<<dim3(32,1,1), 256, 0, stream>>>(xln, Wv + (size_t)l*Hn*INn, Vb,
        nullptr, nullptr, Bn*Tn, Hn, INn, 0,0,0, 0);

    // A = causal_mask(Q @ K^T), per batch
    gemm_nt<<<dim3(4,2,Bn), 256, 0, stream>>>(Qb, Kb, Ab,
        nullptr, nullptr, Tn, Tn, Hn,
        (long long)Tn*Hn, (long long)Tn*Hn, (long long)Tn*Tn, 3);

    den_kernel<<<dim3(Tn,Bn), 256, 0, stream>>>(Ab, Qb, state, den, l);
    attn_num_kernel<<<dim3(4,1,Bn), 256, 0, stream>>>(Ab, Vb, Qb, state, den, attn, l);

    // FF + skip
    gemm_nt<<<dim3(32,1,1), 256, 0, stream>>>(attn, ff_w1 + (size_t)l*Hn*Hn, h1,
        ff_b1 + (size_t)l*Hn, nullptr, Bn*Tn, Hn, Hn, 0,0,0, 2);
    gemm_nt<<<dim3(32,1,1), 256, 0, stream>>>(h1, ff_w2 + (size_t)l*Hn*Hn, tmp2,
        ff_b2 + (size_t)l*Hn, nullptr, Bn*Tn, Hn, Hn, 0,0,0, 2);
    gemm_nt<<<dim3(32,1,1), 256, 0, stream>>>(xln, sc_w + (size_t)l*Hn*INn, x,
        sc_b + (size_t)l*Hn, tmp2, Bn*Tn, Hn, INn, 0,0,0, 0);

    // state updates
    state_S_kernel<<<dim3(4,Bn), 256, 0, stream>>>(Kb, Vb, state, st_out, l);
    state_Z_kernel<<<Bn, 128, 0, stream>>>(Kb, state, st_out, l);
  }

  // y = x @ unmap_w^T + unmap_b, stored (T,B,OUT)
  gemm_nt<<<dim3(32,1,1), 256, 0, stream>>>(x, unmap_w, y_out,
      unmap_b, nullptr, Bn*Tn, OUTn, Hn, 0,0,0, 4);
}

// Round 2
// 191.515 us; speedup vs baseline: 3.8425x; 3.8425x over previous
//
#include <hip/hip_runtime.h>
#include <math.h>

#define Bn 8
#define Tn 256
#define Hn 128
#define Ln 2
#define COREn (Hn*Hn + Hn)      /* 16512 */
#define SDn   (Ln*COREn + 1)    /* 33025 */

static __device__ __forceinline__ void fma4(float4& a, float s, const float4 v) {
  a.x = fmaf(s, v.x, a.x); a.y = fmaf(s, v.y, a.y);
  a.z = fmaf(s, v.z, a.z); a.w = fmaf(s, v.w, a.w);
}
static __device__ __forceinline__ float dot4(const float4 a, const float4 b, float acc) {
  return fmaf(a.x, b.x, fmaf(a.y, b.y, fmaf(a.z, b.z, fmaf(a.w, b.w, acc))));
}

// ============================================================ Kernel A
// rotate(l0) + LN + {K,Q,V,skip} projection.  grid (64, 4), 256 thr.
// by: 0=K(elu+1) 1=Q(elu+1) 2=V 3=skip(xln@scw^T+scb)
__global__ __launch_bounds__(256) void lnproj_kernel(
    const float* __restrict__ xsrc,   // l0: z (T,B,128); else xbuf (B,T,128)
    const float* __restrict__ state,
    const float* __restrict__ Wk, const float* __restrict__ Wq,
    const float* __restrict__ Wv, const float* __restrict__ scw,
    const float* __restrict__ lnw, const float* __restrict__ lnb,
    const float* __restrict__ scb,
    float* __restrict__ Kb, float* __restrict__ Qb,
    float* __restrict__ Vb, float* __restrict__ skipb,
    int is_l0) {
  __shared__ float xs[32][132];
  __shared__ float Ws[128][132];
  __shared__ float redS[32][9];
  __shared__ float redQ[32][9];

  const int tid = threadIdx.x;
  const int by  = blockIdx.y;
  const int g0  = blockIdx.x * 32;

  // ---------- load 32 rows (rotate if l0) ----------
  const int r   = tid >> 3;          // 0..31 local row
  const int seg = tid & 7;           // 16 cols each
  const int g   = g0 + r;
  const int b   = g >> 8;
  const int t   = g & 255;
  const int c0  = seg * 16;

  float v[16];
  const float* src = is_l0 ? (xsrc + ((size_t)t * Bn + b) * 128 + c0)
                           : (xsrc + (size_t)g * 128 + c0);
#pragma unroll
  for (int i = 0; i < 4; i++) {
    float4 f = *(const float4*)(src + i * 4);
    v[i*4+0] = f.x; v[i*4+1] = f.y; v[i*4+2] = f.z; v[i*4+3] = f.w;
  }

  if (is_l0) {
#pragma unroll
    for (int i = 0; i < 16; i++) xs[r][c0 + i] = v[i];   // raw
    __syncthreads();
    float p[16];
    const int pc = c0 ^ 64;
#pragma unroll
    for (int i = 0; i < 16; i++) p[i] = xs[r][pc + i];
    float ts  = state[(size_t)b * SDn + SDn - 1];
    float pos = ts + (float)t;
#pragma unroll
    for (int i = 0; i < 16; i++) {
      int cc = c0 + i;
      int j  = cc & 63;
      float fr  = expf((float)j * -0.14391156831212787f);  // exp(-2j*ln(1e4)/128)
      float ang = pos * fr;
      float sn = sinf(ang), cs = cosf(ang);
      v[i] = (cc < 64) ? (v[i] * cs - p[i] * sn) : (v[i] * cs + p[i] * sn);
    }
    __syncthreads();   // all partner reads done before xs is overwritten below
  }

  // ---------- LN ----------
  float s8 = 0.f, q8 = 0.f;
#pragma unroll
  for (int i = 0; i < 16; i++) { s8 += v[i]; q8 += v[i] * v[i]; }
  redS[r][seg] = s8; redQ[r][seg] = q8;
  __syncthreads();
  if (seg < 4) { redS[r][seg] += redS[r][seg+4]; redQ[r][seg] += redQ[r][seg+4]; }
  __syncthreads();
  if (seg < 2) { redS[r][seg] += redS[r][seg+2]; redQ[r][seg] += redQ[r][seg+2]; }
  __syncthreads();
  float mean = (redS[r][0] + redS[r][1]) * (1.0f / 128.0f);
  float var  = (redQ[r][0] + redQ[r][1]) * (1.0f / 128.0f) - mean * mean;
  float rs   = rsqrtf(var + 1e-5f);
#pragma unroll
  for (int i = 0; i < 16; i++) {
    int cc = c0 + i;
    v[i] = (v[i] - mean) * rs * lnw[cc] + lnb[cc];
    xs[r][cc] = v[i];
  }
  __syncthreads();

  // ---------- load W (full 128x128) ----------
  const float* Wsel = (by == 0) ? Wk : (by == 1) ? Wq : (by == 2) ? Wv : scw;
#pragma unroll
  for (int i = 0; i < 16; i++) {
    int f = tid + i * 256;            // 0..4095
    int n = f >> 5, k4 = f & 31;
    *(float4*)&Ws[n][k4 * 4] = *(const float4*)(Wsel + (size_t)n * 128 + k4 * 4);
  }
  __syncthreads();

  // ---------- GEMM 32x128, 4x4 per thread ----------
  const int rg = tid >> 5;    // rows rg*4..rg*4+3
  const int nc = tid & 31;    // cols nc + 32c
  float acc[4][4] = {};
  for (int k4 = 0; k4 < 32; ++k4) {
    float4 a[4], w[4];
#pragma unroll
    for (int i = 0; i < 4; i++) a[i] = *(const float4*)&xs[rg*4 + i][k4*4];
#pragma unroll
    for (int c = 0; c < 4; c++) w[c] = *(const float4*)&Ws[nc + 32*c][k4*4];
#pragma unroll
    for (int i = 0; i < 4; i++)
#pragma unroll
      for (int c = 0; c < 4; c++)
        acc[i][c] = dot4(a[i], w[c], acc[i][c]);
  }

  float* outp = (by == 0) ? Kb : (by == 1) ? Qb : (by == 2) ? Vb : skipb;
#pragma unroll
  for (int i = 0; i < 4; i++) {
    int gg = g0 + rg*4 + i;
#pragma unroll
    for (int c = 0; c < 4; c++) {
      int n = nc + 32*c;
      float o = acc[i][c];
      if (by < 2)  o = (o > 0.f) ? o + 1.f : expf(o);   // elu+1
      if (by == 3) o += scb[n];
      outp[(size_t)gg * 128 + n] = o;
    }
  }
}

// ============================================================ Kernel B
// blocks 0..127: fused linear attention (16 rows); 128..255: S/Z state update.
__global__ __launch_bounds__(256) void attn_state_kernel(
    const float* __restrict__ Kb, const float* __restrict__ Qb,
    const float* __restrict__ Vb, const float* __restrict__ state,
    float* __restrict__ attn, float* __restrict__ st_out, int l) {
  __shared__ float Ks[32][132];
  __shared__ float Vs[32][132];
  __shared__ float Qs[16][132];
  __shared__ float scs[16][36];
  __shared__ float denp[16][32];
  __shared__ float dens[16];
  __shared__ float Z0s[128];

  const int tid = threadIdx.x;
  const int bx  = blockIdx.x;

  if (bx < 128) {
    // ------------------ attention ------------------
    const int b = bx >> 4, rt = bx & 15, t0 = rt * 16;
#pragma unroll
    for (int i = 0; i < 2; i++) {
      int f = tid + i * 256;          // 512 f4
      int rr = f >> 5, k4 = f & 31;
      *(float4*)&Qs[rr][k4*4] =
          *(const float4*)(Qb + ((size_t)(b*256 + t0 + rr)) * 128 + k4*4);
    }
    if (tid < 128)
      Z0s[tid] = state[(size_t)b * SDn + (size_t)l * COREn + 16384 + tid];
    __syncthreads();

    const int rg = tid >> 5;          // 0..7
    const int cg = tid & 31;          // f4-col index / tau index
    const int r0 = 2 * rg, r1 = r0 + 1;

    float den0 = 0.f, den1 = 0.f;
#pragma unroll
    for (int j = 0; j < 4; j++) {
      den0 += Qs[r0][cg*4 + j] * Z0s[cg*4 + j];
      den1 += Qs[r1][cg*4 + j] * Z0s[cg*4 + j];
    }

    float4 o0 = {0,0,0,0}, o1 = {0,0,0,0};

    // -------- Q @ S0 --------
    const size_t sbase = (size_t)b * SDn + (size_t)l * COREn;
    for (int ic = 0; ic < 128; ic += 32) {
#pragma unroll
      for (int i = 0; i < 16; i++) {        // scalar: state rows not 16B-aligned
        int f = tid + i * 256;              // 4096
        int kk = f >> 7, col = f & 127;
        Ks[kk][col] = state[sbase + (size_t)(ic + kk) * 128 + col];
      }
      __syncthreads();
#pragma unroll 4
      for (int kk = 0; kk < 32; ++kk) {
        float a0 = Qs[r0][ic + kk], a1 = Qs[r1][ic + kk];
        float4 v4 = *(const float4*)&Ks[kk][cg*4];
        fma4(o0, a0, v4); fma4(o1, a1, v4);
      }
      __syncthreads();
    }

    // -------- causal scores + A@V, streamed 32-key chunks --------
    const int nch = ((t0 + 15) >> 5) + 1;
    for (int kc = 0; kc < nch; ++kc) {
      const int kb = kc * 32;
#pragma unroll
      for (int i = 0; i < 4; i++) {
        int f = tid + i * 256;              // 1024 f4 each
        int rr = f >> 5, k4 = f & 31;
        size_t rowoff = ((size_t)(b*256 + kb + rr)) * 128 + k4*4;
        *(float4*)&Ks[rr][k4*4] = *(const float4*)(Kb + rowoff);
        *(float4*)&Vs[rr][k4*4] = *(const float4*)(Vb + rowoff);
      }
      __syncthreads();
      float s0 = 0.f, s1 = 0.f;
      for (int k4 = 0; k4 < 32; ++k4) {
        float4 kv = *(const float4*)&Ks[cg][k4*4];
        float4 q0 = *(const float4*)&Qs[r0][k4*4];
        float4 q1 = *(const float4*)&Qs[r1][k4*4];
        s0 = dot4(q0, kv, s0); s1 = dot4(q1, kv, s1);
      }
      const int tg = kb + cg;
      if (tg > t0 + r0) s0 = 0.f;
      if (tg > t0 + r1) s1 = 0.f;
      den0 += s0; den1 += s1;
      scs[r0][cg] = s0; scs[r1][cg] = s1;
      __syncthreads();
#pragma unroll 4
      for (int kk = 0; kk < 32; ++kk) {
        float c0v = scs[r0][kk], c1v = scs[r1][kk];
        float4 v4 = *(const float4*)&Vs[kk][cg*4];
        fma4(o0, c0v, v4); fma4(o1, c1v, v4);
      }
      __syncthreads();
    }

    // -------- den reduce + store --------
    denp[r0][cg] = den0; denp[r1][cg] = den1;
    __syncthreads();
    if (tid < 16) {
      float d = 1e-5f;
#pragma unroll 8
      for (int c = 0; c < 32; ++c) d += denp[tid][c];
      dens[tid] = d;
    }
    __syncthreads();
    float iv0 = 1.0f / dens[r0], iv1 = 1.0f / dens[r1];
    o0.x *= iv0; o0.y *= iv0; o0.z *= iv0; o0.w *= iv0;
    o1.x *= iv1; o1.y *= iv1; o1.z *= iv1; o1.w *= iv1;
    *(float4*)(attn + ((size_t)(b*256 + t0 + r0)) * 128 + cg*4) = o0;
    *(float4*)(attn + ((size_t)(b*256 + t0 + r1)) * 128 + cg*4) = o1;
  } else {
    // ------------------ state update: S += K^T V ; Z += colsum K ------------------
    const int idx = bx - 128;
    const int b = idx >> 4, tile = idx & 15;
    const int i0 = (tile >> 2) * 32, j0 = (tile & 3) * 32;
    const int ir = tid >> 3;       // 0..31  (i within tile)
    const int jj = tid & 7;        // f4-col within 32 j's
    float4 acc = {0,0,0,0};
    float zacc = 0.f;
    for (int kc = 0; kc < 256; kc += 32) {
#pragma unroll
      for (int i = 0; i < 4; i++) {
        int f = tid + i * 256;
        int rr = f >> 5, k4 = f & 31;
        size_t rowoff = ((size_t)(b*256 + kc + rr)) * 128 + k4*4;
        *(float4*)&Ks[rr][k4*4] = *(const float4*)(Kb + rowoff);
        *(float4*)&Vs[rr][k4*4] = *(const float4*)(Vb + rowoff);
      }
      __syncthreads();
#pragma unroll 4
      for (int kk = 0; kk < 32; ++kk) {
        float kv = Ks[kk][i0 + ir];
        float4 v4 = *(const float4*)&Vs[kk][j0 + jj*4];
        fma4(acc, kv, v4);
        zacc += kv;
      }
      __syncthreads();
    }
    const size_t sb  = (size_t)b * SDn + (size_t)l * COREn;
    const size_t off = sb + (size_t)(i0 + ir) * 128 + j0 + jj*4;
    st_out[off+0] = acc.x + state[off+0];
    st_out[off+1] = acc.y + state[off+1];
    st_out[off+2] = acc.z + state[off+2];
    st_out[off+3] = acc.w + state[off+3];
    if (j0 == 0 && jj == 0) {
      size_t zo = sb + 16384 + i0 + ir;
      st_out[zo] = zacc + state[zo];
    }
    if (l == 0 && tile == 0 && tid == 0)
      st_out[(size_t)b * SDn + SDn - 1] =
          state[(size_t)b * SDn + SDn - 1] + (float)Tn;
  }
}

// ============================================================ Kernel C
// FF1 -> FF2 (+skip) [-> unmap].  grid 256, 8 rows/block.
__global__ __launch_bounds__(256) void ff_kernel(
    const float* __restrict__ attn, const float* __restrict__ skipb,
    const float* __restrict__ w1, const float* __restrict__ b1,
    const float* __restrict__ w2, const float* __restrict__ b2,
    const float* __restrict__ unw, const float* __restrict__ unb,
    float* __restrict__ xout, float* __restrict__ yout, int do_unmap) {
  __shared__ float Ws[128][132];
  __shared__ float as_[8][132];
  __shared__ float h1s[8][132];
  __shared__ float os_[8][132];

  const int tid = threadIdx.x;
  const int g0  = blockIdx.x * 8;

  {
    int rr = tid >> 5, k4 = tid & 31;   // 256 f4 = 8 rows x 32
    *(float4*)&as_[rr][k4*4] =
        *(const float4*)(attn + (size_t)(g0 + rr) * 128 + k4*4);
  }
#pragma unroll
  for (int i = 0; i < 16; i++) {
    int f = tid + i * 256;
    int n = f >> 5, k4 = f & 31;
    *(float4*)&Ws[n][k4*4] = *(const float4*)(w1 + (size_t)n * 128 + k4*4);
  }
  __syncthreads();

  const int rg = tid >> 6;        // 0..3  rows 2rg, 2rg+1
  const int nc = tid & 63;        // cols nc, nc+64
  const int r0 = 2 * rg, r1 = r0 + 1;

  // ---- FF1 ----
  {
    float a00 = 0, a01 = 0, a10 = 0, a11 = 0;
    for (int k4 = 0; k4 < 32; ++k4) {
      float4 x0 = *(const float4*)&as_[r0][k4*4];
      float4 x1 = *(const float4*)&as_[r1][k4*4];
      float4 wA = *(const float4*)&Ws[nc][k4*4];
      float4 wB = *(const float4*)&Ws[nc + 64][k4*4];
      a00 = dot4(x0, wA, a00); a01 = dot4(x0, wB, a01);
      a10 = dot4(x1, wA, a10); a11 = dot4(x1, wB, a11);
    }
    h1s[r0][nc]      = fmaxf(a00 + b1[nc], 0.f);
    h1s[r0][nc + 64] = fmaxf(a01 + b1[nc + 64], 0.f);
    h1s[r1][nc]      = fmaxf(a10 + b1[nc], 0.f);
    h1s[r1][nc + 64] = fmaxf(a11 + b1[nc + 64], 0.f);
  }
  __syncthreads();
#pragma unroll
  for (int i = 0; i < 16; i++) {
    int f = tid + i * 256;
    int n = f >> 5, k4 = f & 31;
    *(float4*)&Ws[n][k4*4] = *(const float4*)(w2 + (size_t)n * 128 + k4*4);
  }
  __syncthreads();

  // ---- FF2 + skip ----
  {
    float a00 = 0, a01 = 0, a10 = 0, a11 = 0;
    for (int k4 = 0; k4 < 32; ++k4) {
      float4 x0 = *(const float4*)&h1s[r0][k4*4];
      float4 x1 = *(const float4*)&h1s[r1][k4*4];
      float4 wA = *(const float4*)&Ws[nc][k4*4];
      float4 wB = *(const float4*)&Ws[nc + 64][k4*4];
      a00 = dot4(x0, wA, a00); a01 = dot4(x0, wB, a01);
      a10 = dot4(x1, wA, a10); a11 = dot4(x1, wB, a11);
    }
    float o00 = fmaxf(a00 + b2[nc], 0.f)      + skipb[(size_t)(g0+r0)*128 + nc];
    float o01 = fmaxf(a01 + b2[nc + 64], 0.f) + skipb[(size_t)(g0+r0)*128 + nc + 64];
    float o10 = fmaxf(a10 + b2[nc], 0.f)      + skipb[(size_t)(g0+r1)*128 + nc];
    float o11 = fmaxf(a11 + b2[nc + 64], 0.f) + skipb[(size_t)(g0+r1)*128 + nc + 64];
    if (!do_unmap) {
      xout[(size_t)(g0+r0)*128 + nc]      = o00;
      xout[(size_t)(g0+r0)*128 + nc + 64] = o01;
      xout[(size_t)(g0+r1)*128 + nc]      = o10;
      xout[(size_t)(g0+r1)*128 + nc + 64] = o11;
      return;
    }
    os_[r0][nc] = o00; os_[r0][nc + 64] = o01;
    os_[r1][nc] = o10; os_[r1][nc + 64] = o11;
  }
  __syncthreads();
#pragma unroll
  for (int i = 0; i < 16; i++) {
    int f = tid + i * 256;
    int n = f >> 5, k4 = f & 31;
    *(float4*)&Ws[n][k4*4] = *(const float4*)(unw + (size_t)n * 128 + k4*4);
  }
  __syncthreads();

  // ---- unmap, store (T,B,OUT) ----
  {
    float a00 = 0, a01 = 0, a10 = 0, a11 = 0;
    for (int k4 = 0; k4 < 32; ++k4) {
      float4 x0 = *(const float4*)&os_[r0][k4*4];
      float4 x1 = *(const float4*)&os_[r1][k4*4];
      float4 wA = *(const float4*)&Ws[nc][k4*4];
      float4 wB = *(const float4*)&Ws[nc + 64][k4*4];
      a00 = dot4(x0, wA, a00); a01 = dot4(x0, wB, a01);
      a10 = dot4(x1, wA, a10); a11 = dot4(x1, wB, a11);
    }
    int gA = g0 + r0, gB = g0 + r1;
    size_t oA = ((size_t)((gA & 255) * Bn + (gA >> 8))) * 128;
    size_t oB = ((size_t)((gB & 255) * Bn + (gB >> 8))) * 128;
    yout[oA + nc]      = a00 + unb[nc];
    yout[oA + nc + 64] = a01 + unb[nc + 64];
    yout[oB + nc]      = a10 + unb[nc];
    yout[oB + nc + 64] = a11 + unb[nc + 64];
  }
}

// ============================================================ launch
extern "C" void kernel_launch(void* const* d_in, const int* in_sizes, int n_in,
                              void* d_out, int out_size, void* d_ws, size_t ws_size,
                              hipStream_t stream) {
  const float* z       = (const float*)d_in[0];
  const float* state   = (const float*)d_in[1];
  const float* Wk      = (const float*)d_in[2];
  const float* Wq      = (const float*)d_in[3];
  const float* Wv      = (const float*)d_in[4];
  const float* ln_w    = (const float*)d_in[5];
  const float* ln_b    = (const float*)d_in[6];
  const float* ff_w1   = (const float*)d_in[7];
  const float* ff_b1   = (const float*)d_in[8];
  const float* ff_w2   = (const float*)d_in[9];
  const float* ff_b2   = (const float*)d_in[10];
  const float* sc_w    = (const float*)d_in[11];
  const float* sc_b    = (const float*)d_in[12];
  const float* unmap_w = (const float*)d_in[13];
  const float* unmap_b = (const float*)d_in[14];

  float* y_out  = (float*)d_out;                       // (T,B,128)
  float* st_out = y_out + (size_t)Tn * Bn * 128;       // (B,SDn)

  const size_t XSZ = (size_t)Bn * Tn * 128;            // 262144
  float* ws    = (float*)d_ws;
  float* Kb    = ws;
  float* Qb    = Kb   + XSZ;
  float* Vb    = Qb   + XSZ;
  float* attnb = Vb   + XSZ;
  float* skipb = attnb + XSZ;
  float* xbuf  = skipb + XSZ;

  for (int l = 0; l < Ln; l++) {
    lnproj_kernel<<<dim3(64, 4), 256, 0, stream>>>(
        (l == 0) ? z : xbuf, state,
        Wk + (size_t)l*Hn*128, Wq + (size_t)l*Hn*128,
        Wv + (size_t)l*Hn*128, sc_w + (size_t)l*Hn*128,
        ln_w + (size_t)l*128, ln_b + (size_t)l*128, sc_b + (size_t)l*Hn,
        Kb, Qb, Vb, skipb, (l == 0) ? 1 : 0);

    attn_state_kernel<<<256, 256, 0, stream>>>(
        Kb, Qb, Vb, state, attnb, st_out, l);

    ff_kernel<<<256, 256, 0, stream>>>(
        attnb, skipb,
        ff_w1 + (size_t)l*Hn*Hn, ff_b1 + (size_t)l*Hn,
        ff_w2 + (size_t)l*Hn*Hn, ff_b2 + (size_t)l*Hn,
        unmap_w, unmap_b,
        xbuf, y_out, (l == 1) ? 1 : 0);
  }
}

// Round 3
// 138.155 us; speedup vs baseline: 5.3265x; 1.3862x over previous
//
#include <hip/hip_runtime.h>
#include <math.h>

#define Bn 8
#define Tn 256
#define Hn 128
#define Ln 2
#define COREn (Hn*Hn + Hn)      /* 16512 */
#define SDn   (Ln*COREn + 1)    /* 33025 */

typedef __attribute__((ext_vector_type(8))) short short8;
typedef __attribute__((ext_vector_type(4))) short short4v;
typedef __attribute__((ext_vector_type(4))) float floatx4;

#define MFMA16(a,b,c) __builtin_amdgcn_mfma_f32_16x16x32_bf16(a,b,c,0,0,0)

static __device__ __forceinline__ unsigned short f2bf(float f) {
  unsigned int u = __float_as_uint(f);
  return (unsigned short)((u + 0x7FFFu + ((u >> 16) & 1u)) >> 16);
}
static __device__ __forceinline__ float bf2f(unsigned short h) {
  return __uint_as_float((unsigned int)h << 16);
}
// load 8 consecutive fp32 from global, convert to bf16 fragment
static __device__ __forceinline__ short8 ldwfrag(const float* p) {
  float4 a = *(const float4*)p;
  float4 b = *(const float4*)(p + 4);
  short8 r;
  r[0] = (short)f2bf(a.x); r[1] = (short)f2bf(a.y);
  r[2] = (short)f2bf(a.z); r[3] = (short)f2bf(a.w);
  r[4] = (short)f2bf(b.x); r[5] = (short)f2bf(b.y);
  r[6] = (short)f2bf(b.z); r[7] = (short)f2bf(b.w);
  return r;
}
static __device__ __forceinline__ void ld8(const float* p, float* v) {
  float4 a = *(const float4*)p, b = *(const float4*)(p + 4);
  v[0]=a.x; v[1]=a.y; v[2]=a.z; v[3]=a.w; v[4]=b.x; v[5]=b.y; v[6]=b.z; v[7]=b.w;
}

// ============================================================ P kernel
// rotate(l0) + LN + one of {K(elu+1), Q(elu+1), V, skip} per blockIdx.y.
// grid (128, 4) x 256 thr. 16 rows per block, MFMA 16x16x32 bf16,
// W fragments read direct from global fp32 with inline cvt.
__global__ __launch_bounds__(256) void proj_kernel(
    const float* __restrict__ xsrc, const float* __restrict__ state,
    const float* __restrict__ Wk, const float* __restrict__ Wq,
    const float* __restrict__ Wv, const float* __restrict__ scw,
    const float* __restrict__ lnw, const float* __restrict__ lnb,
    const float* __restrict__ scb,
    unsigned short* __restrict__ Kb, unsigned short* __restrict__ Kt,
    unsigned short* __restrict__ Qb, unsigned short* __restrict__ Vt,
    float* __restrict__ skipb, int is_l0) {
  __shared__ unsigned short xs[16][136];   // LN'd x, bf16

  const int tid = threadIdx.x;
  const int by  = blockIdx.y;
  const int g0  = blockIdx.x * 16;
  const int r = tid >> 4, c0 = (tid & 15) * 8;
  const int g = g0 + r, b = g >> 8, t = g & 255;

  float v[8];
  if (is_l0) {
    const float* zr = xsrc + ((size_t)t * Bn + b) * 128;
    float pv[8];
    ld8(zr + c0, v);
    ld8(zr + (c0 ^ 64), pv);
    float pos = state[(size_t)b * SDn + SDn - 1] + (float)t;
#pragma unroll
    for (int i = 0; i < 8; i++) {
      int jj = (c0 + i) & 63;
      float ang = pos * expf((float)jj * -0.14391156831212787f);
      float sn = sinf(ang), cs = cosf(ang);
      v[i] = (c0 < 64) ? (v[i] * cs - pv[i] * sn) : (v[i] * cs + pv[i] * sn);
    }
  } else {
    ld8(xsrc + (size_t)g * 128 + c0, v);
  }
  // LN (16 lanes per row, shfl reduce)
  float sm = 0.f, sq = 0.f;
#pragma unroll
  for (int i = 0; i < 8; i++) { sm += v[i]; sq += v[i] * v[i]; }
  for (int d = 8; d; d >>= 1) { sm += __shfl_xor(sm, d, 16); sq += __shfl_xor(sq, d, 16); }
  float mean = sm * (1.f / 128.f);
  float rstd = rsqrtf(sq * (1.f / 128.f) - mean * mean + 1e-5f);
  float lw[8], lb[8];
  ld8(lnw + c0, lw); ld8(lnb + c0, lb);
  short8 xv;
#pragma unroll
  for (int i = 0; i < 8; i++) xv[i] = (short)f2bf((v[i] - mean) * rstd * lw[i] + lb[i]);
  *(short8*)&xs[r][c0] = xv;
  __syncthreads();

  const float* Wsel = (by == 0) ? Wk : (by == 1) ? Wq : (by == 2) ? Wv : scw;
  const int lane = tid & 63, wv = tid >> 6;
  const int lm = lane & 15, quad = lane >> 4;
  floatx4 acc0 = {0.f, 0.f, 0.f, 0.f}, acc1 = {0.f, 0.f, 0.f, 0.f};
#pragma unroll
  for (int kc = 0; kc < 4; kc++) {
    short8 a  = *(const short8*)&xs[lm][kc * 32 + quad * 8];
    short8 b0 = ldwfrag(Wsel + (size_t)(wv * 32 + lm) * 128 + kc * 32 + quad * 8);
    short8 b1 = ldwfrag(Wsel + (size_t)(wv * 32 + 16 + lm) * 128 + kc * 32 + quad * 8);
    acc0 = MFMA16(a, b0, acc0);
    acc1 = MFMA16(a, b1, acc1);
  }
  // epilogue: rows quad*4+j, cols wv*32+lm and wv*32+16+lm
  const int t0l = g0 & 255;
  const int n0 = wv * 32 + lm, n1 = wv * 32 + 16 + lm;
  if (by == 0) {          // K: elu+1, store K row-major + K^T
    short4v kt0, kt1;
#pragma unroll
    for (int j = 0; j < 4; j++) {
      int row = quad * 4 + j;
      float e0 = acc0[j] > 0.f ? acc0[j] + 1.f : expf(acc0[j]);
      float e1 = acc1[j] > 0.f ? acc1[j] + 1.f : expf(acc1[j]);
      Kb[(size_t)(g0 + row) * 128 + n0] = f2bf(e0);
      Kb[(size_t)(g0 + row) * 128 + n1] = f2bf(e1);
      kt0[j] = (short)f2bf(e0); kt1[j] = (short)f2bf(e1);
    }
    *(short4v*)(Kt + (size_t)(b * 128 + n0) * 256 + t0l + quad * 4) = kt0;
    *(short4v*)(Kt + (size_t)(b * 128 + n1) * 256 + t0l + quad * 4) = kt1;
  } else if (by == 1) {   // Q: elu+1, row-major
#pragma unroll
    for (int j = 0; j < 4; j++) {
      int row = quad * 4 + j;
      float e0 = acc0[j] > 0.f ? acc0[j] + 1.f : expf(acc0[j]);
      float e1 = acc1[j] > 0.f ? acc1[j] + 1.f : expf(acc1[j]);
      Qb[(size_t)(g0 + row) * 128 + n0] = f2bf(e0);
      Qb[(size_t)(g0 + row) * 128 + n1] = f2bf(e1);
    }
  } else if (by == 2) {   // V: store V^T only
    short4v v0, v1;
#pragma unroll
    for (int j = 0; j < 4; j++) { v0[j] = (short)f2bf(acc0[j]); v1[j] = (short)f2bf(acc1[j]); }
    *(short4v*)(Vt + (size_t)(b * 128 + n0) * 256 + t0l + quad * 4) = v0;
    *(short4v*)(Vt + (size_t)(b * 128 + n1) * 256 + t0l + quad * 4) = v1;
  } else {                // skip: fp32
    float sb0 = scb[n0], sb1 = scb[n1];
#pragma unroll
    for (int j = 0; j < 4; j++) {
      int row = quad * 4 + j;
      skipb[(size_t)(g0 + row) * 128 + n0] = acc0[j] + sb0;
      skipb[(size_t)(g0 + row) * 128 + n1] = acc1[j] + sb1;
    }
  }
}

// ============================================================ A kernel
// blocks 0..127: attention (16 Q-rows each; waves own causal chunks
// independently — no syncs in main loop). blocks 128..255: S/Z update.
__global__ __launch_bounds__(256) void attn_state_kernel(
    const unsigned short* __restrict__ Kb, const unsigned short* __restrict__ Kt,
    const unsigned short* __restrict__ Qb, const unsigned short* __restrict__ Vt,
    const float* __restrict__ state, unsigned short* __restrict__ attnb,
    float* __restrict__ st_out, int l) {
  const int tid = threadIdx.x, bx = blockIdx.x;
  const int lane = tid & 63, wv = tid >> 6, lm = lane & 15, quad = lane >> 4;

  if (bx < 128) {
    __shared__ unsigned short xs[16][136];     // Q tile bf16
    __shared__ unsigned short Ssc[4][16][40];  // per-wave masked scores bf16
    __shared__ float Obuf[4][16][132];         // per-wave O accum
    __shared__ float Z0s[128];
    __shared__ float denw[4][16];
    __shared__ float denz[16];
    __shared__ float dinv[16];

    const int b = bx >> 4, rt = bx & 15, t0 = rt * 16;
    const size_t sb = (size_t)b * SDn + (size_t)l * COREn;
    {
      int r = tid >> 4, c = (tid & 15) * 8;
      *(short8*)&xs[r][c] = *(const short8*)(Qb + (size_t)(b * 256 + t0 + r) * 128 + c);
    }
    if (tid < 128) Z0s[tid] = state[sb + 16384 + tid];
    __syncthreads();

    // den += Q . Z0 (fp32)
    {
      int r = tid >> 4, c = (tid & 15) * 8;
      float qz = 0.f;
#pragma unroll
      for (int i = 0; i < 8; i++) qz += bf2f(xs[r][c + i]) * Z0s[c + i];
      for (int d = 8; d; d >>= 1) qz += __shfl_xor(qz, d, 16);
      if ((tid & 15) == 0) denz[r] = qz;
    }

    floatx4 oacc[8];
#pragma unroll
    for (int jt = 0; jt < 8; jt++) oacc[jt] = floatx4{0.f, 0.f, 0.f, 0.f};
    float dacc[4] = {0.f, 0.f, 0.f, 0.f};

    const int nch = rt / 2 + 1;
    for (int c = wv; c < nch; c += 4) {
      const int kb = c * 32;
      floatx4 s0 = {0.f,0.f,0.f,0.f}, s1 = {0.f,0.f,0.f,0.f};
#pragma unroll
      for (int kc = 0; kc < 4; kc++) {
        short8 a  = *(const short8*)&xs[lm][kc * 32 + quad * 8];
        short8 k0 = *(const short8*)(Kb + (size_t)(b * 256 + kb + lm) * 128 + kc * 32 + quad * 8);
        short8 k1 = *(const short8*)(Kb + (size_t)(b * 256 + kb + 16 + lm) * 128 + kc * 32 + quad * 8);
        s0 = MFMA16(a, k0, s0);
        s1 = MFMA16(a, k1, s1);
      }
      const int tau0 = kb + lm, tau1 = kb + 16 + lm;
#pragma unroll
      for (int j = 0; j < 4; j++) {
        int m = t0 + quad * 4 + j;
        float v0 = (tau0 <= m) ? s0[j] : 0.f;
        float v1 = (tau1 <= m) ? s1[j] : 0.f;
        dacc[j] += v0 + v1;
        Ssc[wv][quad * 4 + j][lm]      = f2bf(v0);
        Ssc[wv][quad * 4 + j][16 + lm] = f2bf(v1);
      }
      // P (bf16, A-layout) @ V^T fragments
      short8 sa = *(const short8*)&Ssc[wv][lm][quad * 8];
#pragma unroll
      for (int jt = 0; jt < 8; jt++) {
        short8 vb = *(const short8*)(Vt + (size_t)(b * 128 + jt * 16 + lm) * 256 + kb + quad * 8);
        oacc[jt] = MFMA16(sa, vb, oacc[jt]);
      }
    }

    // Q @ S0 : wave wv takes i in [wv*32, wv*32+32)
    {
      const float* S0 = state + sb;
      short8 aq = *(const short8*)&xs[lm][wv * 32 + quad * 8];
#pragma unroll
      for (int jt = 0; jt < 8; jt++) {
        short8 vb;
#pragma unroll
        for (int jj = 0; jj < 8; jj++)
          vb[jj] = (short)f2bf(S0[(size_t)(wv * 32 + quad * 8 + jj) * 128 + jt * 16 + lm]);
        oacc[jt] = MFMA16(aq, vb, oacc[jt]);
      }
    }

    // reduce den across the 16 lanes of each quad
#pragma unroll
    for (int j = 0; j < 4; j++)
      for (int d = 8; d; d >>= 1) dacc[j] += __shfl_xor(dacc[j], d, 16);
    if (lm == 0) {
#pragma unroll
      for (int j = 0; j < 4; j++) denw[wv][quad * 4 + j] = dacc[j];
    }
#pragma unroll
    for (int jt = 0; jt < 8; jt++)
#pragma unroll
      for (int j = 0; j < 4; j++)
        Obuf[wv][quad * 4 + j][jt * 16 + lm] = oacc[jt][j];
    __syncthreads();
    if (tid < 16) {
      float d = denz[tid] + denw[0][tid] + denw[1][tid] + denw[2][tid] + denw[3][tid] + 1e-5f;
      dinv[tid] = 1.f / d;
    }
    __syncthreads();
    {
      int r = tid >> 4, c = (tid & 15) * 8;
      float di = dinv[r];
      short8 ov;
#pragma unroll
      for (int i = 0; i < 8; i++) {
        float o = Obuf[0][r][c + i] + Obuf[1][r][c + i] + Obuf[2][r][c + i] + Obuf[3][r][c + i];
        ov[i] = (short)f2bf(o * di);
      }
      *(short8*)(attnb + (size_t)(b * 256 + t0 + r) * 128 + c) = ov;
    }
  } else {
    // ---------------- state: S += K^T V ; Z += colsum K ; ts += 256
    const int idx = bx - 128;
    const int b = idx >> 4, sub = idx & 15;
    const int i0 = (sub >> 1) * 16, j0 = (sub & 1) * 64;
    const size_t sb = (size_t)b * SDn + (size_t)l * COREn;
    floatx4 acc = {0.f, 0.f, 0.f, 0.f};
#pragma unroll
    for (int kc = 0; kc < 8; kc++) {
      short8 ka = *(const short8*)(Kt + (size_t)(b * 128 + i0 + lm) * 256 + kc * 32 + quad * 8);
      short8 vb = *(const short8*)(Vt + (size_t)(b * 128 + j0 + wv * 16 + lm) * 256 + kc * 32 + quad * 8);
      acc = MFMA16(ka, vb, acc);
    }
#pragma unroll
    for (int j = 0; j < 4; j++) {
      size_t off = sb + (size_t)(i0 + quad * 4 + j) * 128 + j0 + wv * 16 + lm;
      st_out[off] = acc[j] + state[off];
    }
    if (j0 == 0) {
      if (tid < 128) {
        int i = tid >> 3, seg = tid & 7;
        const unsigned short* kr = Kt + (size_t)(b * 128 + i0 + i) * 256 + seg * 32;
        float zs = 0.f;
#pragma unroll
        for (int x = 0; x < 4; x++) {
          short8 kv = *(const short8*)(kr + x * 8);
#pragma unroll
          for (int y = 0; y < 8; y++) zs += bf2f((unsigned short)kv[y]);
        }
        for (int d = 4; d; d >>= 1) zs += __shfl_xor(zs, d, 8);
        if (seg == 0) {
          size_t zo = sb + 16384 + i0 + i;
          st_out[zo] = zs + state[zo];
        }
      }
      if (sub == 0 && tid == 0 && l == 0)
        st_out[(size_t)b * SDn + SDn - 1] = state[(size_t)b * SDn + SDn - 1] + 256.f;
    }
  }
}

// ============================================================ F kernel
// ff1 -> ff2 + skip [-> unmap].  grid 128 x 256 thr, 16 rows per block.
__global__ __launch_bounds__(256) void ff_kernel(
    const unsigned short* __restrict__ attnb, const float* __restrict__ skipb,
    const float* __restrict__ w1, const float* __restrict__ b1,
    const float* __restrict__ w2, const float* __restrict__ b2,
    const float* __restrict__ unw, const float* __restrict__ unb,
    float* __restrict__ xout, float* __restrict__ yout, int do_unmap) {
  __shared__ unsigned short xs[16][136];
  __shared__ unsigned short hs[16][136];
  __shared__ float sk[16][132];

  const int tid = threadIdx.x;
  const int g0 = blockIdx.x * 16;
  const int lane = tid & 63, wv = tid >> 6, lm = lane & 15, quad = lane >> 4;
  const int n0 = wv * 32 + lm, n1 = wv * 32 + 16 + lm;

  {
    int r = tid >> 4, c = (tid & 15) * 8;
    *(short8*)&xs[r][c] = *(const short8*)(attnb + (size_t)(g0 + r) * 128 + c);
#pragma unroll
    for (int p = 0; p < 2; p++) {
      int f = tid + p * 256;
      int rr = f >> 5, cc = (f & 31) * 4;
      *(float4*)&sk[rr][cc] = *(const float4*)(skipb + (size_t)(g0 + rr) * 128 + cc);
    }
  }
  __syncthreads();

  // ---- GEMM1: h1 = relu(attn @ w1^T + b1)
  {
    floatx4 a0 = {0.f,0.f,0.f,0.f}, a1 = {0.f,0.f,0.f,0.f};
#pragma unroll
    for (int kc = 0; kc < 4; kc++) {
      short8 a  = *(const short8*)&xs[lm][kc * 32 + quad * 8];
      short8 bA = ldwfrag(w1 + (size_t)n0 * 128 + kc * 32 + quad * 8);
      short8 bB = ldwfrag(w1 + (size_t)n1 * 128 + kc * 32 + quad * 8);
      a0 = MFMA16(a, bA, a0);
      a1 = MFMA16(a, bB, a1);
    }
    float bi0 = b1[n0], bi1 = b1[n1];
#pragma unroll
    for (int j = 0; j < 4; j++) {
      int row = quad * 4 + j;
      hs[row][n0] = f2bf(fmaxf(a0[j] + bi0, 0.f));
      hs[row][n1] = f2bf(fmaxf(a1[j] + bi1, 0.f));
    }
  }
  __syncthreads();

  // ---- GEMM2: o = relu(h1 @ w2^T + b2) + skip
  float o0[4], o1[4];
  {
    floatx4 a0 = {0.f,0.f,0.f,0.f}, a1 = {0.f,0.f,0.f,0.f};
#pragma unroll
    for (int kc = 0; kc < 4; kc++) {
      short8 a  = *(const short8*)&hs[lm][kc * 32 + quad * 8];
      short8 bA = ldwfrag(w2 + (size_t)n0 * 128 + kc * 32 + quad * 8);
      short8 bB = ldwfrag(w2 + (size_t)n1 * 128 + kc * 32 + quad * 8);
      a0 = MFMA16(a, bA, a0);
      a1 = MFMA16(a, bB, a1);
    }
    float bi0 = b2[n0], bi1 = b2[n1];
#pragma unroll
    for (int j = 0; j < 4; j++) {
      int row = quad * 4 + j;
      o0[j] = fmaxf(a0[j] + bi0, 0.f) + sk[row][n0];
      o1[j] = fmaxf(a1[j] + bi1, 0.f) + sk[row][n1];
    }
  }
  if (!do_unmap) {
#pragma unroll
    for (int j = 0; j < 4; j++) {
      int row = quad * 4 + j;
      xout[(size_t)(g0 + row) * 128 + n0] = o0[j];
      xout[(size_t)(g0 + row) * 128 + n1] = o1[j];
    }
    return;
  }
  __syncthreads();   // all GEMM2 hs-reads done before xs overwrite? (xs unused in GEMM2; sync guards xs reuse ordering)
#pragma unroll
  for (int j = 0; j < 4; j++) {
    int row = quad * 4 + j;
    xs[row][n0] = f2bf(o0[j]);
    xs[row][n1] = f2bf(o1[j]);
  }
  __syncthreads();
  // ---- GEMM3: y = o @ unw^T + unb, store (T,B,128)
  {
    floatx4 a0 = {0.f,0.f,0.f,0.f}, a1 = {0.f,0.f,0.f,0.f};
#pragma unroll
    for (int kc = 0; kc < 4; kc++) {
      short8 a  = *(const short8*)&xs[lm][kc * 32 + quad * 8];
      short8 bA = ldwfrag(unw + (size_t)n0 * 128 + kc * 32 + quad * 8);
      short8 bB = ldwfrag(unw + (size_t)n1 * 128 + kc * 32 + quad * 8);
      a0 = MFMA16(a, bA, a0);
      a1 = MFMA16(a, bB, a1);
    }
    float u0 = unb[n0], u1 = unb[n1];
#pragma unroll
    for (int j = 0; j < 4; j++) {
      int gg = g0 + quad * 4 + j;
      int bb = gg >> 8, tq = gg & 255;
      yout[(size_t)(tq * Bn + bb) * 128 + n0] = a0[j] + u0;
      yout[(size_t)(tq * Bn + bb) * 128 + n1] = a1[j] + u1;
    }
  }
}

// ============================================================ launch
extern "C" void kernel_launch(void* const* d_in, const int* in_sizes, int n_in,
                              void* d_out, int out_size, void* d_ws, size_t ws_size,
                              hipStream_t stream) {
  const float* z       = (const float*)d_in[0];
  const float* state   = (const float*)d_in[1];
  const float* Wk      = (const float*)d_in[2];
  const float* Wq      = (const float*)d_in[3];
  const float* Wv      = (const float*)d_in[4];
  const float* ln_w    = (const float*)d_in[5];
  const float* ln_b    = (const float*)d_in[6];
  const float* ff_w1   = (const float*)d_in[7];
  const float* ff_b1   = (const float*)d_in[8];
  const float* ff_w2   = (const float*)d_in[9];
  const float* ff_b2   = (const float*)d_in[10];
  const float* sc_w    = (const float*)d_in[11];
  const float* sc_b    = (const float*)d_in[12];
  const float* unmap_w = (const float*)d_in[13];
  const float* unmap_b = (const float*)d_in[14];

  float* y_out  = (float*)d_out;                      // (T,B,128)
  float* st_out = y_out + (size_t)Tn * Bn * 128;      // (B,SDn)

  const size_t E = 262144;                            // 2048*128
  unsigned short* Kb    = (unsigned short*)d_ws;
  unsigned short* Qb    = Kb + E;
  unsigned short* Kt    = Qb + E;                     // (B,128,256) bf16
  unsigned short* Vt    = Kt + E;                     // (B,128,256) bf16
  unsigned short* attnb = Vt + E;
  float* skipb = (float*)(attnb + E);
  float* xbuf  = skipb + E;

  for (int l = 0; l < Ln; l++) {
    proj_kernel<<<dim3(128, 4), 256, 0, stream>>>(
        (l == 0) ? z : xbuf, state,
        Wk + (size_t)l * 16384, Wq + (size_t)l * 16384,
        Wv + (size_t)l * 16384, sc_w + (size_t)l * 16384,
        ln_w + (size_t)l * 128, ln_b + (size_t)l * 128, sc_b + (size_t)l * 128,
        Kb, Kt, Qb, Vt, skipb, (l == 0) ? 1 : 0);

    attn_state_kernel<<<256, 256, 0, stream>>>(
        Kb, Kt, Qb, Vt, state, attnb, st_out, l);

    ff_kernel<<<128, 256, 0, stream>>>(
        attnb, skipb,
        ff_w1 + (size_t)l * 16384, ff_b1 + (size_t)l * 128,
        ff_w2 + (size_t)l * 16384, ff_b2 + (size_t)l * 128,
        unmap_w, unmap_b, xbuf, y_out, (l == 1) ? 1 : 0);
  }
}

// Round 5
// 135.625 us; speedup vs baseline: 5.4259x; 1.0187x over previous
//
#include <hip/hip_runtime.h>
#include <math.h>

#define Bn 8
#define Tn 256
#define COREn 16512
#define SDn   33025

typedef __attribute__((ext_vector_type(8))) short short8;
typedef __attribute__((ext_vector_type(4))) short short4v;
typedef __attribute__((ext_vector_type(4))) float floatx4;

#define MFMA16(a,b,c) __builtin_amdgcn_mfma_f32_16x16x32_bf16(a,b,c,0,0,0)

static __device__ __forceinline__ unsigned short f2bf(float f) {
  unsigned int u = __float_as_uint(f);
  return (unsigned short)((u + 0x7FFFu + ((u >> 16) & 1u)) >> 16);
}
static __device__ __forceinline__ float bf2f(unsigned short h) {
  return __uint_as_float((unsigned int)h << 16);
}
static __device__ __forceinline__ short8 ldwfrag(const float* p) {
  float4 a = *(const float4*)p;
  float4 b = *(const float4*)(p + 4);
  short8 r;
  r[0] = (short)f2bf(a.x); r[1] = (short)f2bf(a.y);
  r[2] = (short)f2bf(a.z); r[3] = (short)f2bf(a.w);
  r[4] = (short)f2bf(b.x); r[5] = (short)f2bf(b.y);
  r[6] = (short)f2bf(b.z); r[7] = (short)f2bf(b.w);
  return r;
}
static __device__ __forceinline__ void ld8(const float* p, float* v) {
  float4 a = *(const float4*)p, b = *(const float4*)(p + 4);
  v[0]=a.x; v[1]=a.y; v[2]=a.z; v[3]=a.w; v[4]=b.x; v[5]=b.y; v[6]=b.z; v[7]=b.w;
}

struct Phase1 {                     // attention accumulation
  unsigned short Ssc[4][16][40];
  float Obuf[4][16][132];
  float denw[4][16];
};
struct Phase2 {                     // ff / ln phase
  float sk[16][132];
  float os[16][132];
};
struct Smem {
  unsigned short xs[16][136];
  unsigned short xattn[16][136];
  unsigned short hs[16][136];
  float Z0s[128];
  float denz[16];
  float dinv[16];
  union { Phase1 p1; Phase2 p2; } u;
};                                  // 52,864 B

// --------------------------------------------------------- proj epilogue
// by: 0=K(elu+1, Kb+Kt) 1=Q(elu+1) 2=V(Vt) 3=skip(+scb, fp32)
static __device__ __forceinline__ void proj_epilogue(
    int by, int g0, int b, int t0l, int n0, int n1, int quad,
    floatx4 acc0, floatx4 acc1,
    unsigned short* __restrict__ Kb, unsigned short* __restrict__ Kt,
    unsigned short* __restrict__ Qb, unsigned short* __restrict__ Vt,
    float* __restrict__ skipb, const float* __restrict__ scb) {
  if (by == 0) {
    short4v kt0, kt1;
#pragma unroll
    for (int j = 0; j < 4; j++) {
      int row = quad * 4 + j;
      float e0 = acc0[j] > 0.f ? acc0[j] + 1.f : expf(acc0[j]);
      float e1 = acc1[j] > 0.f ? acc1[j] + 1.f : expf(acc1[j]);
      Kb[(size_t)(g0 + row) * 128 + n0] = f2bf(e0);
      Kb[(size_t)(g0 + row) * 128 + n1] = f2bf(e1);
      kt0[j] = (short)f2bf(e0); kt1[j] = (short)f2bf(e1);
    }
    *(short4v*)(Kt + (size_t)(b * 128 + n0) * 256 + t0l + quad * 4) = kt0;
    *(short4v*)(Kt + (size_t)(b * 128 + n1) * 256 + t0l + quad * 4) = kt1;
  } else if (by == 1) {
#pragma unroll
    for (int j = 0; j < 4; j++) {
      int row = quad * 4 + j;
      float e0 = acc0[j] > 0.f ? acc0[j] + 1.f : expf(acc0[j]);
      float e1 = acc1[j] > 0.f ? acc1[j] + 1.f : expf(acc1[j]);
      Qb[(size_t)(g0 + row) * 128 + n0] = f2bf(e0);
      Qb[(size_t)(g0 + row) * 128 + n1] = f2bf(e1);
    }
  } else if (by == 2) {
    short4v v0, v1;
#pragma unroll
    for (int j = 0; j < 4; j++) { v0[j] = (short)f2bf(acc0[j]); v1[j] = (short)f2bf(acc1[j]); }
    *(short4v*)(Vt + (size_t)(b * 128 + n0) * 256 + t0l + quad * 4) = v0;
    *(short4v*)(Vt + (size_t)(b * 128 + n1) * 256 + t0l + quad * 4) = v1;
  } else {
    float sb0 = scb[n0], sb1 = scb[n1];
#pragma unroll
    for (int j = 0; j < 4; j++) {
      int row = quad * 4 + j;
      skipb[(size_t)(g0 + row) * 128 + n0] = acc0[j] + sb0;
      skipb[(size_t)(g0 + row) * 128 + n1] = acc1[j] + sb1;
    }
  }
}

// --------------------------------------------------------- attn + ff (+proj l1 | +unmap)
static __device__ void attn_ff(
    Smem& s, int tid, int b, int rt, int l,
    const unsigned short* __restrict__ Kb, const unsigned short* __restrict__ Qb,
    const unsigned short* __restrict__ Vt,
    const float* __restrict__ state, const float* __restrict__ skipin,
    const float* __restrict__ w1, const float* __restrict__ b1,
    const float* __restrict__ w2, const float* __restrict__ b2,
    const float* __restrict__ Wk1, const float* __restrict__ Wq1,
    const float* __restrict__ Wv1, const float* __restrict__ scw1,
    const float* __restrict__ lnw1, const float* __restrict__ lnb1,
    const float* __restrict__ scb1,
    unsigned short* __restrict__ Kb1, unsigned short* __restrict__ Kt1,
    unsigned short* __restrict__ Qb1, unsigned short* __restrict__ Vt1,
    float* __restrict__ skip1,
    const float* __restrict__ unw, const float* __restrict__ unb,
    float* __restrict__ yout) {
  const int lane = tid & 63, wv = tid >> 6, lm = lane & 15, quad = lane >> 4;
  const int t0 = rt * 16;
  const size_t sb = (size_t)b * SDn + (size_t)l * COREn;

  { int r = tid >> 4, c = (tid & 15) * 8;
    *(short8*)&s.xs[r][c] = *(const short8*)(Qb + (size_t)(b * 256 + t0 + r) * 128 + c); }
  if (tid < 128) s.Z0s[tid] = state[sb + 16384 + tid];
  __syncthreads();

  { int r = tid >> 4, c = (tid & 15) * 8;
    float qz = 0.f;
#pragma unroll
    for (int i = 0; i < 8; i++) qz += bf2f(s.xs[r][c + i]) * s.Z0s[c + i];
    for (int d = 8; d; d >>= 1) qz += __shfl_xor(qz, d, 16);
    if ((tid & 15) == 0) s.denz[r] = qz; }

  floatx4 oacc[8];
#pragma unroll
  for (int jt = 0; jt < 8; jt++) oacc[jt] = floatx4{0.f, 0.f, 0.f, 0.f};
  float dacc[4] = {0.f, 0.f, 0.f, 0.f};

  const int nch = rt / 2 + 1;
  for (int c = wv; c < nch; c += 4) {
    const int kb = c * 32;
    floatx4 s0 = {0.f,0.f,0.f,0.f}, s1 = {0.f,0.f,0.f,0.f};
#pragma unroll
    for (int kc = 0; kc < 4; kc++) {
      short8 a  = *(const short8*)&s.xs[lm][kc * 32 + quad * 8];
      short8 k0 = *(const short8*)(Kb + (size_t)(b * 256 + kb + lm) * 128 + kc * 32 + quad * 8);
      short8 k1 = *(const short8*)(Kb + (size_t)(b * 256 + kb + 16 + lm) * 128 + kc * 32 + quad * 8);
      s0 = MFMA16(a, k0, s0);
      s1 = MFMA16(a, k1, s1);
    }
    const int tau0 = kb + lm, tau1 = kb + 16 + lm;
#pragma unroll
    for (int j = 0; j < 4; j++) {
      int m = t0 + quad * 4 + j;
      float v0 = (tau0 <= m) ? s0[j] : 0.f;
      float v1 = (tau1 <= m) ? s1[j] : 0.f;
      dacc[j] += v0 + v1;
      s.u.p1.Ssc[wv][quad * 4 + j][lm]      = f2bf(v0);
      s.u.p1.Ssc[wv][quad * 4 + j][16 + lm] = f2bf(v1);
    }
    short8 sa = *(const short8*)&s.u.p1.Ssc[wv][lm][quad * 8];
#pragma unroll
    for (int jt = 0; jt < 8; jt++) {
      short8 vb = *(const short8*)(Vt + (size_t)(b * 128 + jt * 16 + lm) * 256 + kb + quad * 8);
      oacc[jt] = MFMA16(sa, vb, oacc[jt]);
    }
  }

  { const float* S0 = state + sb;
    short8 aq = *(const short8*)&s.xs[lm][wv * 32 + quad * 8];
#pragma unroll
    for (int jt = 0; jt < 8; jt++) {
      short8 vb;
#pragma unroll
      for (int jj = 0; jj < 8; jj++)
        vb[jj] = (short)f2bf(S0[(size_t)(wv * 32 + quad * 8 + jj) * 128 + jt * 16 + lm]);
      oacc[jt] = MFMA16(aq, vb, oacc[jt]);
    } }

#pragma unroll
  for (int j = 0; j < 4; j++)
    for (int d = 8; d; d >>= 1) dacc[j] += __shfl_xor(dacc[j], d, 16);
  if (lm == 0) {
#pragma unroll
    for (int j = 0; j < 4; j++) s.u.p1.denw[wv][quad * 4 + j] = dacc[j];
  }
#pragma unroll
  for (int jt = 0; jt < 8; jt++)
#pragma unroll
    for (int j = 0; j < 4; j++)
      s.u.p1.Obuf[wv][quad * 4 + j][jt * 16 + lm] = oacc[jt][j];
  __syncthreads();
  if (tid < 16)
    s.dinv[tid] = 1.f / (s.denz[tid] + s.u.p1.denw[0][tid] + s.u.p1.denw[1][tid]
                         + s.u.p1.denw[2][tid] + s.u.p1.denw[3][tid] + 1e-5f);
  __syncthreads();
  { int r = tid >> 4, c = (tid & 15) * 8;
    float di = s.dinv[r];
    short8 ov;
#pragma unroll
    for (int i = 0; i < 8; i++) {
      float o = s.u.p1.Obuf[0][r][c + i] + s.u.p1.Obuf[1][r][c + i]
              + s.u.p1.Obuf[2][r][c + i] + s.u.p1.Obuf[3][r][c + i];
      ov[i] = (short)f2bf(o * di);
    }
    *(short8*)&s.xattn[r][c] = ov; }
  __syncthreads();            // Obuf dead -> Phase2 usable

  const int gr0 = b * 256 + t0;
#pragma unroll
  for (int p = 0; p < 2; p++) {       // stage skip rows (fp32)
    int f = tid + p * 256;
    int rr = f >> 5, cc = (f & 31) * 4;
    *(float4*)&s.u.p2.sk[rr][cc] = *(const float4*)(skipin + (size_t)(gr0 + rr) * 128 + cc);
  }
  const int n0 = wv * 32 + lm, n1 = n0 + 16;

  // ---- FF1
  { floatx4 a0 = {0.f,0.f,0.f,0.f}, a1 = {0.f,0.f,0.f,0.f};
#pragma unroll
    for (int kc = 0; kc < 4; kc++) {
      short8 a  = *(const short8*)&s.xattn[lm][kc * 32 + quad * 8];
      short8 bA = ldwfrag(w1 + (size_t)n0 * 128 + kc * 32 + quad * 8);
      short8 bB = ldwfrag(w1 + (size_t)n1 * 128 + kc * 32 + quad * 8);
      a0 = MFMA16(a, bA, a0);
      a1 = MFMA16(a, bB, a1);
    }
    float bi0 = b1[n0], bi1 = b1[n1];
#pragma unroll
    for (int j = 0; j < 4; j++) {
      int row = quad * 4 + j;
      s.hs[row][n0] = f2bf(fmaxf(a0[j] + bi0, 0.f));
      s.hs[row][n1] = f2bf(fmaxf(a1[j] + bi1, 0.f));
    } }
  __syncthreads();

  // ---- FF2 + skip
  float o0[4], o1[4];
  { floatx4 a0 = {0.f,0.f,0.f,0.f}, a1 = {0.f,0.f,0.f,0.f};
#pragma unroll
    for (int kc = 0; kc < 4; kc++) {
      short8 a  = *(const short8*)&s.hs[lm][kc * 32 + quad * 8];
      short8 bA = ldwfrag(w2 + (size_t)n0 * 128 + kc * 32 + quad * 8);
      short8 bB = ldwfrag(w2 + (size_t)n1 * 128 + kc * 32 + quad * 8);
      a0 = MFMA16(a, bA, a0);
      a1 = MFMA16(a, bB, a1);
    }
    float bi0 = b2[n0], bi1 = b2[n1];
#pragma unroll
    for (int j = 0; j < 4; j++) {
      int row = quad * 4 + j;
      o0[j] = fmaxf(a0[j] + bi0, 0.f) + s.u.p2.sk[row][n0];
      o1[j] = fmaxf(a1[j] + bi1, 0.f) + s.u.p2.sk[row][n1];
    } }

  if (l == 0) {
    // ---- LN + proj layer 1 (row-local)
#pragma unroll
    for (int j = 0; j < 4; j++) {
      int row = quad * 4 + j;
      s.u.p2.os[row][n0] = o0[j];
      s.u.p2.os[row][n1] = o1[j];
    }
    __syncthreads();
    { int r = tid >> 4, c0 = (tid & 15) * 8;
      float v[8];
#pragma unroll
      for (int i = 0; i < 8; i++) v[i] = s.u.p2.os[r][c0 + i];
      float sm = 0.f, sq = 0.f;
#pragma unroll
      for (int i = 0; i < 8; i++) { sm += v[i]; sq += v[i] * v[i]; }
      for (int d = 8; d; d >>= 1) { sm += __shfl_xor(sm, d, 16); sq += __shfl_xor(sq, d, 16); }
      float mean = sm * (1.f / 128.f);
      float rstd = rsqrtf(sq * (1.f / 128.f) - mean * mean + 1e-5f);
      short8 xv;
#pragma unroll
      for (int i = 0; i < 8; i++)
        xv[i] = (short)f2bf((v[i] - mean) * rstd * lnw1[c0 + i] + lnb1[c0 + i]);
      *(short8*)&s.xs[r][c0] = xv; }
    __syncthreads();
#pragma unroll
    for (int by = 0; by < 4; by++) {
      const float* W = by == 0 ? Wk1 : by == 1 ? Wq1 : by == 2 ? Wv1 : scw1;
      floatx4 a0 = {0.f,0.f,0.f,0.f}, a1 = {0.f,0.f,0.f,0.f};
#pragma unroll
      for (int kc = 0; kc < 4; kc++) {
        short8 a  = *(const short8*)&s.xs[lm][kc * 32 + quad * 8];
        short8 bA = ldwfrag(W + (size_t)n0 * 128 + kc * 32 + quad * 8);
        short8 bB = ldwfrag(W + (size_t)n1 * 128 + kc * 32 + quad * 8);
        a0 = MFMA16(a, bA, a0);
        a1 = MFMA16(a, bB, a1);
      }
      proj_epilogue(by, gr0, b, t0, n0, n1, quad, a0, a1,
                    Kb1, Kt1, Qb1, Vt1, skip1, scb1);
    }
  } else {
    // ---- unmap -> y (T,B,128)
#pragma unroll
    for (int j = 0; j < 4; j++) {
      int row = quad * 4 + j;
      s.xs[row][n0] = f2bf(o0[j]);
      s.xs[row][n1] = f2bf(o1[j]);
    }
    __syncthreads();
    floatx4 a0 = {0.f,0.f,0.f,0.f}, a1 = {0.f,0.f,0.f,0.f};
#pragma unroll
    for (int kc = 0; kc < 4; kc++) {
      short8 a  = *(const short8*)&s.xs[lm][kc * 32 + quad * 8];
      short8 bA = ldwfrag(unw + (size_t)n0 * 128 + kc * 32 + quad * 8);
      short8 bB = ldwfrag(unw + (size_t)n1 * 128 + kc * 32 + quad * 8);
      a0 = MFMA16(a, bA, a0);
      a1 = MFMA16(a, bB, a1);
    }
    float u0 = unb[n0], u1 = unb[n1];
#pragma unroll
    for (int j = 0; j < 4; j++) {
      int gg = gr0 + quad * 4 + j;
      int bb = gg >> 8, tq = gg & 255;
      yout[(size_t)(tq * Bn + bb) * 128 + n0] = a0[j] + u0;
      yout[(size_t)(tq * Bn + bb) * 128 + n1] = a1[j] + u1;
    }
  }
}

// --------------------------------------------------------- state update
static __device__ void state_upd(
    int tid, int idx, int l,
    const unsigned short* __restrict__ Kt, const unsigned short* __restrict__ Vt,
    const float* __restrict__ state, float* __restrict__ st_out) {
  const int lane = tid & 63, wv = tid >> 6, lm = lane & 15, quad = lane >> 4;
  const int b = idx >> 4, sub = idx & 15;
  const int i0 = (sub >> 1) * 16, j0 = (sub & 1) * 64;
  const size_t sb = (size_t)b * SDn + (size_t)l * COREn;
  floatx4 acc = {0.f, 0.f, 0.f, 0.f};
#pragma unroll
  for (int kc = 0; kc < 8; kc++) {
    short8 ka = *(const short8*)(Kt + (size_t)(b * 128 + i0 + lm) * 256 + kc * 32 + quad * 8);
    short8 vb = *(const short8*)(Vt + (size_t)(b * 128 + j0 + wv * 16 + lm) * 256 + kc * 32 + quad * 8);
    acc = MFMA16(ka, vb, acc);
  }
#pragma unroll
  for (int j = 0; j < 4; j++) {
    size_t off = sb + (size_t)(i0 + quad * 4 + j) * 128 + j0 + wv * 16 + lm;
    st_out[off] = acc[j] + state[off];
  }
  if (j0 == 0) {
    if (tid < 128) {
      int i = tid >> 3, seg = tid & 7;
      const unsigned short* kr = Kt + (size_t)(b * 128 + i0 + i) * 256 + seg * 32;
      float zs = 0.f;
#pragma unroll
      for (int x = 0; x < 4; x++) {
        short8 kv = *(const short8*)(kr + x * 8);
#pragma unroll
        for (int y = 0; y < 8; y++) zs += bf2f((unsigned short)kv[y]);
      }
      for (int d = 4; d; d >>= 1) zs += __shfl_xor(zs, d, 8);
      if (seg == 0) {
        size_t zo = sb + 16384 + i0 + i;
        st_out[zo] = zs + state[zo];
      }
    }
    if (sub == 0 && tid == 0 && l == 0)
      st_out[(size_t)b * SDn + SDn - 1] = state[(size_t)b * SDn + SDn - 1] + 256.f;
  }
}

// =========================================================== kernel 1: proj l0
__global__ __launch_bounds__(256) void proj0_kernel(
    const float* __restrict__ z, const float* __restrict__ state,
    const float* __restrict__ Wk, const float* __restrict__ Wq,
    const float* __restrict__ Wv, const float* __restrict__ scw,
    const float* __restrict__ lnw, const float* __restrict__ lnb,
    const float* __restrict__ scb,
    unsigned short* __restrict__ Kb0, unsigned short* __restrict__ Qb0,
    unsigned short* __restrict__ Kt0, unsigned short* __restrict__ Vt0,
    float* __restrict__ skip0) {
  __shared__ unsigned short xs[16][136];
  const int tid = threadIdx.x, bx = blockIdx.x;
  const int lane = tid & 63, wv = tid >> 6, lm = lane & 15, quad = lane >> 4;
  const int tile = bx >> 1, half = bx & 1;
  const int g0 = tile * 16;
  const int r = tid >> 4, c0 = (tid & 15) * 8;
  const int g = g0 + r, b = g >> 8, t = g & 255;
  float v[8], pv[8];
  const float* zr = z + ((size_t)t * Bn + b) * 128;
  ld8(zr + c0, v);
  ld8(zr + (c0 ^ 64), pv);
  float pos = state[(size_t)b * SDn + SDn - 1] + (float)t;
#pragma unroll
  for (int i = 0; i < 8; i++) {
    int jj = (c0 + i) & 63;
    float ang = pos * expf((float)jj * -0.14391156831212787f);
    float sn = sinf(ang), cs = cosf(ang);
    v[i] = (c0 < 64) ? (v[i] * cs - pv[i] * sn) : (v[i] * cs + pv[i] * sn);
  }
  float sm = 0.f, sq = 0.f;
#pragma unroll
  for (int i = 0; i < 8; i++) { sm += v[i]; sq += v[i] * v[i]; }
  for (int d = 8; d; d >>= 1) { sm += __shfl_xor(sm, d, 16); sq += __shfl_xor(sq, d, 16); }
  float mean = sm * (1.f / 128.f);
  float rstd = rsqrtf(sq * (1.f / 128.f) - mean * mean + 1e-5f);
  short8 xv;
#pragma unroll
  for (int i = 0; i < 8; i++)
    xv[i] = (short)f2bf((v[i] - mean) * rstd * lnw[c0 + i] + lnb[c0 + i]);
  *(short8*)&xs[r][c0] = xv;
  __syncthreads();

  const int bb = g0 >> 8, t0l = g0 & 255;
  const int n0 = wv * 32 + lm, n1 = n0 + 16;
#pragma unroll
  for (int which = 0; which < 2; which++) {
    const float* W = half == 0 ? (which == 0 ? Wk : Wq)
                               : (which == 0 ? Wv : scw);
    floatx4 a0 = {0.f,0.f,0.f,0.f}, a1 = {0.f,0.f,0.f,0.f};
#pragma unroll
    for (int kc = 0; kc < 4; kc++) {
      short8 a  = *(const short8*)&xs[lm][kc * 32 + quad * 8];
      short8 bA = ldwfrag(W + (size_t)n0 * 128 + kc * 32 + quad * 8);
      short8 bB = ldwfrag(W + (size_t)n1 * 128 + kc * 32 + quad * 8);
      a0 = MFMA16(a, bA, a0);
      a1 = MFMA16(a, bB, a1);
    }
    proj_epilogue(half * 2 + which, g0, bb, t0l, n0, n1, quad, a0, a1,
                  Kb0, Kt0, Qb0, Vt0, skip0, scb);
  }
}

// =========================================================== kernel 2: layer 0
__global__ __launch_bounds__(256) void layer0_kernel(
    const unsigned short* __restrict__ Kb0, const unsigned short* __restrict__ Qb0,
    const unsigned short* __restrict__ Kt0, const unsigned short* __restrict__ Vt0,
    const float* __restrict__ skip0, const float* __restrict__ state,
    const float* __restrict__ w1, const float* __restrict__ b1,
    const float* __restrict__ w2, const float* __restrict__ b2,
    const float* __restrict__ Wk1, const float* __restrict__ Wq1,
    const float* __restrict__ Wv1, const float* __restrict__ scw1,
    const float* __restrict__ lnw1, const float* __restrict__ lnb1,
    const float* __restrict__ scb1,
    unsigned short* __restrict__ Kb1, unsigned short* __restrict__ Kt1,
    unsigned short* __restrict__ Qb1, unsigned short* __restrict__ Vt1,
    float* __restrict__ skip1, float* __restrict__ st_out) {
  __shared__ Smem s;
  const int tid = threadIdx.x, bx = blockIdx.x;
  if (bx < 128)
    attn_ff(s, tid, bx >> 4, bx & 15, 0,
            Kb0, Qb0, Vt0, state, skip0,
            w1, b1, w2, b2,
            Wk1, Wq1, Wv1, scw1, lnw1, lnb1, scb1,
            Kb1, Kt1, Qb1, Vt1, skip1,
            nullptr, nullptr, nullptr);
  else
    state_upd(tid, bx - 128, 0, Kt0, Vt0, state, st_out);
}

// =========================================================== kernel 3: layer 1
__global__ __launch_bounds__(256) void layer1_kernel(
    const unsigned short* __restrict__ Kb1, const unsigned short* __restrict__ Qb1,
    const unsigned short* __restrict__ Kt1, const unsigned short* __restrict__ Vt1,
    const float* __restrict__ skip1, const float* __restrict__ state,
    const float* __restrict__ w1, const float* __restrict__ b1,
    const float* __restrict__ w2, const float* __restrict__ b2,
    const float* __restrict__ unw, const float* __restrict__ unb,
    float* __restrict__ yout, float* __restrict__ st_out) {
  __shared__ Smem s;
  const int tid = threadIdx.x, bx = blockIdx.x;
  if (bx < 128)
    attn_ff(s, tid, bx >> 4, bx & 15, 1,
            Kb1, Qb1, Vt1, state, skip1,
            w1, b1, w2, b2,
            nullptr, nullptr, nullptr, nullptr, nullptr, nullptr, nullptr,
            nullptr, nullptr, nullptr, nullptr, nullptr,
            unw, unb, yout);
  else
    state_upd(tid, bx - 128, 1, Kt1, Vt1, state, st_out);
}

// ============================================================ launch
extern "C" void kernel_launch(void* const* d_in, const int* in_sizes, int n_in,
                              void* d_out, int out_size, void* d_ws, size_t ws_size,
                              hipStream_t stream) {
  const float* z       = (const float*)d_in[0];
  const float* state   = (const float*)d_in[1];
  const float* Wk      = (const float*)d_in[2];
  const float* Wq      = (const float*)d_in[3];
  const float* Wv      = (const float*)d_in[4];
  const float* ln_w    = (const float*)d_in[5];
  const float* ln_b    = (const float*)d_in[6];
  const float* ff_w1   = (const float*)d_in[7];
  const float* ff_b1   = (const float*)d_in[8];
  const float* ff_w2   = (const float*)d_in[9];
  const float* ff_b2   = (const float*)d_in[10];
  const float* sc_w    = (const float*)d_in[11];
  const float* sc_b    = (const float*)d_in[12];
  const float* unmap_w = (const float*)d_in[13];
  const float* unmap_b = (const float*)d_in[14];

  float* y_out  = (float*)d_out;                      // (T,B,128)
  float* st_out = y_out + (size_t)Tn * Bn * 128;      // (B,SDn)

  const size_t E = 262144;                            // 2048*128
  unsigned short* Kb0 = (unsigned short*)d_ws;
  unsigned short* Qb0 = Kb0 + E;
  unsigned short* Kt0 = Qb0 + E;
  unsigned short* Vt0 = Kt0 + E;
  unsigned short* Kb1 = Vt0 + E;
  unsigned short* Qb1 = Kb1 + E;
  unsigned short* Kt1 = Qb1 + E;
  unsigned short* Vt1 = Kt1 + E;
  float* skip0 = (float*)(Vt1 + E);
  float* skip1 = skip0 + E;

  proj0_kernel<<<256, 256, 0, stream>>>(
      z, state, Wk, Wq, Wv, sc_w, ln_w, ln_b, sc_b,
      Kb0, Qb0, Kt0, Vt0, skip0);

  layer0_kernel<<<256, 256, 0, stream>>>(
      Kb0, Qb0, Kt0, Vt0, skip0, state,
      ff_w1, ff_b1, ff_w2, ff_b2,
      Wk + 16384, Wq + 16384, Wv + 16384, sc_w + 16384,
      ln_w + 128, ln_b + 128, sc_b + 128,
      Kb1, Kt1, Qb1, Vt1, skip1, st_out);

  layer1_kernel<<<256, 256, 0, stream>>>(
      Kb1, Qb1, Kt1, Vt1, skip1, state,
      ff_w1 + 16384, ff_b1 + 128, ff_w2 + 16384, ff_b2 + 128,
      unmap_w, unmap_b, y_out, st_out);
}

// Round 6
// 130.415 us; speedup vs baseline: 5.6427x; 1.0399x over previous
//
#include <hip/hip_runtime.h>
#include <math.h>

#define Bn 8
#define Tn 256
#define COREn 16512
#define SDn   33025

typedef __attribute__((ext_vector_type(8))) short short8;
typedef __attribute__((ext_vector_type(4))) short short4v;
typedef __attribute__((ext_vector_type(4))) float floatx4;

#define MFMA16(a,b,c) __builtin_amdgcn_mfma_f32_16x16x32_bf16(a,b,c,0,0,0)

static __device__ __forceinline__ unsigned short f2bf(float f) {
  unsigned int u = __float_as_uint(f);
  return (unsigned short)((u + 0x7FFFu + ((u >> 16) & 1u)) >> 16);
}
static __device__ __forceinline__ float bf2f(unsigned short h) {
  return __uint_as_float((unsigned int)h << 16);
}
static __device__ __forceinline__ short8 ldwfrag(const float* p) {
  float4 a = *(const float4*)p;
  float4 b = *(const float4*)(p + 4);
  short8 r;
  r[0] = (short)f2bf(a.x); r[1] = (short)f2bf(a.y);
  r[2] = (short)f2bf(a.z); r[3] = (short)f2bf(a.w);
  r[4] = (short)f2bf(b.x); r[5] = (short)f2bf(b.y);
  r[6] = (short)f2bf(b.z); r[7] = (short)f2bf(b.w);
  return r;
}
static __device__ __forceinline__ void ld8(const float* p, float* v) {
  float4 a = *(const float4*)p, b = *(const float4*)(p + 4);
  v[0]=a.x; v[1]=a.y; v[2]=a.z; v[3]=a.w; v[4]=b.x; v[5]=b.y; v[6]=b.z; v[7]=b.w;
}

// --------------------------------------------------------- proj epilogue
// by: 0=K(elu+1, Kb+Kt) 1=Q(elu+1) 2=V(Vt) 3=skip(+scb, bf16)
static __device__ __forceinline__ void proj_epilogue(
    int by, int g0, int b, int t0l, int n0, int n1, int quad,
    floatx4 acc0, floatx4 acc1,
    unsigned short* __restrict__ Kb, unsigned short* __restrict__ Kt,
    unsigned short* __restrict__ Qb, unsigned short* __restrict__ Vt,
    unsigned short* __restrict__ skipb, const float* __restrict__ scb) {
  if (by == 0) {
    short4v kt0, kt1;
#pragma unroll
    for (int j = 0; j < 4; j++) {
      int row = quad * 4 + j;
      float e0 = acc0[j] > 0.f ? acc0[j] + 1.f : expf(acc0[j]);
      float e1 = acc1[j] > 0.f ? acc1[j] + 1.f : expf(acc1[j]);
      Kb[(size_t)(g0 + row) * 128 + n0] = f2bf(e0);
      Kb[(size_t)(g0 + row) * 128 + n1] = f2bf(e1);
      kt0[j] = (short)f2bf(e0); kt1[j] = (short)f2bf(e1);
    }
    *(short4v*)(Kt + (size_t)(b * 128 + n0) * 256 + t0l + quad * 4) = kt0;
    *(short4v*)(Kt + (size_t)(b * 128 + n1) * 256 + t0l + quad * 4) = kt1;
  } else if (by == 1) {
#pragma unroll
    for (int j = 0; j < 4; j++) {
      int row = quad * 4 + j;
      float e0 = acc0[j] > 0.f ? acc0[j] + 1.f : expf(acc0[j]);
      float e1 = acc1[j] > 0.f ? acc1[j] + 1.f : expf(acc1[j]);
      Qb[(size_t)(g0 + row) * 128 + n0] = f2bf(e0);
      Qb[(size_t)(g0 + row) * 128 + n1] = f2bf(e1);
    }
  } else if (by == 2) {
    short4v v0, v1;
#pragma unroll
    for (int j = 0; j < 4; j++) { v0[j] = (short)f2bf(acc0[j]); v1[j] = (short)f2bf(acc1[j]); }
    *(short4v*)(Vt + (size_t)(b * 128 + n0) * 256 + t0l + quad * 4) = v0;
    *(short4v*)(Vt + (size_t)(b * 128 + n1) * 256 + t0l + quad * 4) = v1;
  } else {
    float sb0 = scb[n0], sb1 = scb[n1];
#pragma unroll
    for (int j = 0; j < 4; j++) {
      int row = quad * 4 + j;
      skipb[(size_t)(g0 + row) * 128 + n0] = f2bf(acc0[j] + sb0);
      skipb[(size_t)(g0 + row) * 128 + n1] = f2bf(acc1[j] + sb1);
    }
  }
}

// =========================================================== prep: proj l0 (512) + S0t (16)
__global__ __launch_bounds__(256) void prep_kernel(
    const float* __restrict__ z, const float* __restrict__ state,
    const float* __restrict__ Wk, const float* __restrict__ Wq,
    const float* __restrict__ Wv, const float* __restrict__ scw,
    const float* __restrict__ lnw, const float* __restrict__ lnb,
    const float* __restrict__ scb,
    unsigned short* __restrict__ Kb0, unsigned short* __restrict__ Qb0,
    unsigned short* __restrict__ Kt0, unsigned short* __restrict__ Vt0,
    unsigned short* __restrict__ skip0, unsigned short* __restrict__ S0t) {
  const int tid = threadIdx.x, bx = blockIdx.x;
  if (bx < 512) {
    __shared__ unsigned short xs[16][136];
    const int lane = tid & 63, wv = tid >> 6, lm = lane & 15, quad = lane >> 4;
    const int tile = bx >> 2, by = bx & 3;
    const int g0 = tile * 16;
    const int r = tid >> 4, c0 = (tid & 15) * 8;
    const int g = g0 + r, b = g >> 8, t = g & 255;
    float v[8], pv[8];
    const float* zr = z + ((size_t)t * Bn + b) * 128;
    ld8(zr + c0, v);
    ld8(zr + (c0 ^ 64), pv);
    float pos = state[(size_t)b * SDn + SDn - 1] + (float)t;
#pragma unroll
    for (int i = 0; i < 8; i++) {
      int jj = (c0 + i) & 63;
      float ang = pos * expf((float)jj * -0.14391156831212787f);
      float sn = sinf(ang), cs = cosf(ang);
      v[i] = (c0 < 64) ? (v[i] * cs - pv[i] * sn) : (v[i] * cs + pv[i] * sn);
    }
    float sm = 0.f, sq = 0.f;
#pragma unroll
    for (int i = 0; i < 8; i++) { sm += v[i]; sq += v[i] * v[i]; }
    for (int d = 8; d; d >>= 1) { sm += __shfl_xor(sm, d, 16); sq += __shfl_xor(sq, d, 16); }
    float mean = sm * (1.f / 128.f);
    float rstd = rsqrtf(sq * (1.f / 128.f) - mean * mean + 1e-5f);
    short8 xv;
#pragma unroll
    for (int i = 0; i < 8; i++)
      xv[i] = (short)f2bf((v[i] - mean) * rstd * lnw[c0 + i] + lnb[c0 + i]);
    *(short8*)&xs[r][c0] = xv;
    __syncthreads();

    const float* W = by == 0 ? Wk : by == 1 ? Wq : by == 2 ? Wv : scw;
    const int bb = g0 >> 8, t0l = g0 & 255;
    const int n0 = wv * 32 + lm, n1 = n0 + 16;
    floatx4 a0 = {0.f,0.f,0.f,0.f}, a1 = {0.f,0.f,0.f,0.f};
#pragma unroll
    for (int kc = 0; kc < 4; kc++) {
      short8 a  = *(const short8*)&xs[lm][kc * 32 + quad * 8];
      short8 bA = ldwfrag(W + (size_t)n0 * 128 + kc * 32 + quad * 8);
      short8 bB = ldwfrag(W + (size_t)n1 * 128 + kc * 32 + quad * 8);
      a0 = MFMA16(a, bA, a0);
      a1 = MFMA16(a, bB, a1);
    }
    proj_epilogue(by, g0, bb, t0l, n0, n1, quad, a0, a1,
                  Kb0, Kt0, Qb0, Vt0, skip0, scb);
  } else {
    // ------- S0 -> S0t (bf16, transposed), both layers -------
    __shared__ float tl[32][33];
    const int id = bx - 512, b = id >> 1, l = id & 1;
    const float* src = state + (size_t)b * SDn + (size_t)l * COREn;
    unsigned short* dst = S0t + (size_t)(l * 8 + b) * 16384;
    const int r = tid >> 3, c4 = (tid & 7) * 4;
#pragma unroll
    for (int tI = 0; tI < 4; tI++)
      for (int tJ = 0; tJ < 4; tJ++) {
        int i0 = tI * 32, j0 = tJ * 32;
#pragma unroll
        for (int q = 0; q < 4; q++)
          tl[r][c4 + q] = src[(size_t)(i0 + r) * 128 + j0 + c4 + q];
        __syncthreads();
        short4v o;
#pragma unroll
        for (int q = 0; q < 4; q++) o[q] = (short)f2bf(tl[c4 + q][r]);
        *(short4v*)(dst + (size_t)(j0 + r) * 128 + i0 + c4) = o;
        __syncthreads();
      }
  }
}

// =========================================================== state update (device fn)
static __device__ void state_upd(
    int tid, int idx, int l,
    const unsigned short* __restrict__ Kt, const unsigned short* __restrict__ Vt,
    const float* __restrict__ state, float* __restrict__ st_out) {
  const int lane = tid & 63, wv = tid >> 6, lm = lane & 15, quad = lane >> 4;
  const int b = idx >> 4, sub = idx & 15;
  const int i0 = (sub >> 1) * 16, j0 = (sub & 1) * 64;
  const size_t sb = (size_t)b * SDn + (size_t)l * COREn;
  floatx4 acc = {0.f, 0.f, 0.f, 0.f};
#pragma unroll
  for (int kc = 0; kc < 8; kc++) {
    short8 ka = *(const short8*)(Kt + (size_t)(b * 128 + i0 + lm) * 256 + kc * 32 + quad * 8);
    short8 vb = *(const short8*)(Vt + (size_t)(b * 128 + j0 + wv * 16 + lm) * 256 + kc * 32 + quad * 8);
    acc = MFMA16(ka, vb, acc);
  }
#pragma unroll
  for (int j = 0; j < 4; j++) {
    size_t off = sb + (size_t)(i0 + quad * 4 + j) * 128 + j0 + wv * 16 + lm;
    st_out[off] = acc[j] + state[off];
  }
  if (j0 == 0) {
    if (tid < 128) {
      int i = tid >> 3, seg = tid & 7;
      const unsigned short* kr = Kt + (size_t)(b * 128 + i0 + i) * 256 + seg * 32;
      float zs = 0.f;
#pragma unroll
      for (int x = 0; x < 4; x++) {
        short8 kv = *(const short8*)(kr + x * 8);
#pragma unroll
        for (int y = 0; y < 8; y++) zs += bf2f((unsigned short)kv[y]);
      }
      for (int d = 4; d; d >>= 1) zs += __shfl_xor(zs, d, 8);
      if (seg == 0) {
        size_t zo = sb + 16384 + i0 + i;
        st_out[zo] = zs + state[zo];
      }
    }
    if (sub == 0 && tid == 0 && l == 0)
      st_out[(size_t)b * SDn + SDn - 1] = state[(size_t)b * SDn + SDn - 1] + 256.f;
  }
}

// =========================================================== attention (256 col-split) + state (128)
__global__ __launch_bounds__(256) void attn_kernel(
    const unsigned short* __restrict__ Kb, const unsigned short* __restrict__ Qb,
    const unsigned short* __restrict__ Vt, const unsigned short* __restrict__ Kt,
    const unsigned short* __restrict__ S0tl, const float* __restrict__ state,
    unsigned short* __restrict__ attnb, float* __restrict__ st_out, int l) {
  const int tid = threadIdx.x, bx = blockIdx.x;
  const int lane = tid & 63, wv = tid >> 6, lm = lane & 15, quad = lane >> 4;
  if (bx < 256) {
    __shared__ unsigned short xs[16][136];
    __shared__ unsigned short Ssc[4][16][40];
    __shared__ float Obuf[4][16][68];
    __shared__ float Z0s[128];
    __shared__ float denw[4][16];
    __shared__ float denz[16];
    __shared__ float dinv[16];

    const int tile = bx >> 1, half = bx & 1;
    const int b = tile >> 4, rt = tile & 15, t0 = rt * 16;
    const size_t sb = (size_t)b * SDn + (size_t)l * COREn;
    { int r = tid >> 4, c = (tid & 15) * 8;
      *(short8*)&xs[r][c] = *(const short8*)(Qb + (size_t)(b * 256 + t0 + r) * 128 + c); }
    if (tid < 128) Z0s[tid] = state[sb + 16384 + tid];
    __syncthreads();

    { int r = tid >> 4, c = (tid & 15) * 8;
      float qz = 0.f;
#pragma unroll
      for (int i = 0; i < 8; i++) qz += bf2f(xs[r][c + i]) * Z0s[c + i];
      for (int d = 8; d; d >>= 1) qz += __shfl_xor(qz, d, 16);
      if ((tid & 15) == 0) denz[r] = qz; }

    floatx4 oacc[4];
#pragma unroll
    for (int jt = 0; jt < 4; jt++) oacc[jt] = floatx4{0.f, 0.f, 0.f, 0.f};
    float dacc[4] = {0.f, 0.f, 0.f, 0.f};

    const int nch = rt / 2 + 1;
    for (int c = wv; c < nch; c += 4) {
      const int kb = c * 32;
      short8 vfr[4];
#pragma unroll
      for (int jt = 0; jt < 4; jt++)
        vfr[jt] = *(const short8*)(Vt + (size_t)(b * 128 + half * 64 + jt * 16 + lm) * 256 + kb + quad * 8);
      floatx4 s0 = {0.f,0.f,0.f,0.f}, s1 = {0.f,0.f,0.f,0.f};
#pragma unroll
      for (int kc = 0; kc < 4; kc++) {
        short8 a  = *(const short8*)&xs[lm][kc * 32 + quad * 8];
        short8 k0 = *(const short8*)(Kb + (size_t)(b * 256 + kb + lm) * 128 + kc * 32 + quad * 8);
        short8 k1 = *(const short8*)(Kb + (size_t)(b * 256 + kb + 16 + lm) * 128 + kc * 32 + quad * 8);
        s0 = MFMA16(a, k0, s0);
        s1 = MFMA16(a, k1, s1);
      }
      const int tau0 = kb + lm, tau1 = kb + 16 + lm;
#pragma unroll
      for (int j = 0; j < 4; j++) {
        int m = t0 + quad * 4 + j;
        float v0 = (tau0 <= m) ? s0[j] : 0.f;
        float v1 = (tau1 <= m) ? s1[j] : 0.f;
        dacc[j] += v0 + v1;
        Ssc[wv][quad * 4 + j][lm]      = f2bf(v0);
        Ssc[wv][quad * 4 + j][16 + lm] = f2bf(v1);
      }
      short8 sa = *(const short8*)&Ssc[wv][lm][quad * 8];
#pragma unroll
      for (int jt = 0; jt < 4; jt++)
        oacc[jt] = MFMA16(sa, vfr[jt], oacc[jt]);
    }

    // Q @ S0 via pre-transposed bf16 S0t
    { short8 aq = *(const short8*)&xs[lm][wv * 32 + quad * 8];
#pragma unroll
      for (int jt = 0; jt < 4; jt++) {
        short8 vb = *(const short8*)(S0tl + (size_t)b * 16384 +
                        (size_t)(half * 64 + jt * 16 + lm) * 128 + wv * 32 + quad * 8);
        oacc[jt] = MFMA16(aq, vb, oacc[jt]);
      } }

#pragma unroll
    for (int j = 0; j < 4; j++)
      for (int d = 8; d; d >>= 1) dacc[j] += __shfl_xor(dacc[j], d, 16);
    if (lm == 0) {
#pragma unroll
      for (int j = 0; j < 4; j++) denw[wv][quad * 4 + j] = dacc[j];
    }
#pragma unroll
    for (int jt = 0; jt < 4; jt++)
#pragma unroll
      for (int j = 0; j < 4; j++)
        Obuf[wv][quad * 4 + j][jt * 16 + lm] = oacc[jt][j];
    __syncthreads();
    if (tid < 16)
      dinv[tid] = 1.f / (denz[tid] + denw[0][tid] + denw[1][tid]
                         + denw[2][tid] + denw[3][tid] + 1e-5f);
    __syncthreads();
    { int r = tid >> 4, c = (tid & 15) * 4;
      float di = dinv[r];
      short4v ov;
#pragma unroll
      for (int q = 0; q < 4; q++) {
        float o = Obuf[0][r][c + q] + Obuf[1][r][c + q]
                + Obuf[2][r][c + q] + Obuf[3][r][c + q];
        ov[q] = (short)f2bf(o * di);
      }
      *(short4v*)(attnb + (size_t)(b * 256 + t0 + r) * 128 + half * 64 + c) = ov; }
  } else {
    state_upd(tid, bx - 256, l, Kt, Vt, state, st_out);
  }
}

// =========================================================== FF + LN -> xln1  (128 blocks)
__global__ __launch_bounds__(256) void ffln_kernel(
    const unsigned short* __restrict__ attnb, const unsigned short* __restrict__ skipb,
    const float* __restrict__ w1, const float* __restrict__ b1,
    const float* __restrict__ w2, const float* __restrict__ b2,
    const float* __restrict__ lnw1, const float* __restrict__ lnb1,
    unsigned short* __restrict__ xln1) {
  __shared__ unsigned short xa[16][136];
  __shared__ unsigned short hs[16][136];
  __shared__ float os[16][132];
  const int tid = threadIdx.x, g0 = blockIdx.x * 16;
  const int lane = tid & 63, wv = tid >> 6, lm = lane & 15, quad = lane >> 4;
  const int n0 = wv * 32 + lm, n1 = n0 + 16;

  // early independent loads: weight frags, biases, skip
  short8 w1A[4], w1B[4], w2A[4], w2B[4];
#pragma unroll
  for (int kc = 0; kc < 4; kc++) {
    w1A[kc] = ldwfrag(w1 + (size_t)n0 * 128 + kc * 32 + quad * 8);
    w1B[kc] = ldwfrag(w1 + (size_t)n1 * 128 + kc * 32 + quad * 8);
    w2A[kc] = ldwfrag(w2 + (size_t)n0 * 128 + kc * 32 + quad * 8);
    w2B[kc] = ldwfrag(w2 + (size_t)n1 * 128 + kc * 32 + quad * 8);
  }
  float bi10 = b1[n0], bi11 = b1[n1], bi20 = b2[n0], bi21 = b2[n1];
  float sk0[4], sk1[4];
#pragma unroll
  for (int j = 0; j < 4; j++) {
    sk0[j] = bf2f(skipb[(size_t)(g0 + quad * 4 + j) * 128 + n0]);
    sk1[j] = bf2f(skipb[(size_t)(g0 + quad * 4 + j) * 128 + n1]);
  }
  { int r = tid >> 4, c = (tid & 15) * 8;
    *(short8*)&xa[r][c] = *(const short8*)(attnb + (size_t)(g0 + r) * 128 + c); }
  __syncthreads();

  { floatx4 a0 = {0.f,0.f,0.f,0.f}, a1 = {0.f,0.f,0.f,0.f};
#pragma unroll
    for (int kc = 0; kc < 4; kc++) {
      short8 a = *(const short8*)&xa[lm][kc * 32 + quad * 8];
      a0 = MFMA16(a, w1A[kc], a0);
      a1 = MFMA16(a, w1B[kc], a1);
    }
#pragma unroll
    for (int j = 0; j < 4; j++) {
      int row = quad * 4 + j;
      hs[row][n0] = f2bf(fmaxf(a0[j] + bi10, 0.f));
      hs[row][n1] = f2bf(fmaxf(a1[j] + bi11, 0.f));
    } }
  __syncthreads();
  { floatx4 a0 = {0.f,0.f,0.f,0.f}, a1 = {0.f,0.f,0.f,0.f};
#pragma unroll
    for (int kc = 0; kc < 4; kc++) {
      short8 a = *(const short8*)&hs[lm][kc * 32 + quad * 8];
      a0 = MFMA16(a, w2A[kc], a0);
      a1 = MFMA16(a, w2B[kc], a1);
    }
#pragma unroll
    for (int j = 0; j < 4; j++) {
      int row = quad * 4 + j;
      os[row][n0] = fmaxf(a0[j] + bi20, 0.f) + sk0[j];
      os[row][n1] = fmaxf(a1[j] + bi21, 0.f) + sk1[j];
    } }
  __syncthreads();
  { int r = tid >> 4, c0 = (tid & 15) * 8;
    float v[8];
#pragma unroll
    for (int i = 0; i < 8; i++) v[i] = os[r][c0 + i];
    float sm = 0.f, sq = 0.f;
#pragma unroll
    for (int i = 0; i < 8; i++) { sm += v[i]; sq += v[i] * v[i]; }
    for (int d = 8; d; d >>= 1) { sm += __shfl_xor(sm, d, 16); sq += __shfl_xor(sq, d, 16); }
    float mean = sm * (1.f / 128.f);
    float rstd = rsqrtf(sq * (1.f / 128.f) - mean * mean + 1e-5f);
    short8 xv;
#pragma unroll
    for (int i = 0; i < 8; i++)
      xv[i] = (short)f2bf((v[i] - mean) * rstd * lnw1[c0 + i] + lnb1[c0 + i]);
    *(short8*)(xln1 + (size_t)(g0 + r) * 128 + c0) = xv; }
}

// =========================================================== proj l1 (512 blocks)
__global__ __launch_bounds__(256) void proj1_kernel(
    const unsigned short* __restrict__ xln1,
    const float* __restrict__ Wk, const float* __restrict__ Wq,
    const float* __restrict__ Wv, const float* __restrict__ scw,
    const float* __restrict__ scb,
    unsigned short* __restrict__ Kb1, unsigned short* __restrict__ Qb1,
    unsigned short* __restrict__ Kt1, unsigned short* __restrict__ Vt1,
    unsigned short* __restrict__ skip1) {
  __shared__ unsigned short xs[16][136];
  const int tid = threadIdx.x, bx = blockIdx.x;
  const int lane = tid & 63, wv = tid >> 6, lm = lane & 15, quad = lane >> 4;
  const int tile = bx >> 2, by = bx & 3;
  const int g0 = tile * 16;
  { int r = tid >> 4, c = (tid & 15) * 8;
    *(short8*)&xs[r][c] = *(const short8*)(xln1 + (size_t)(g0 + r) * 128 + c); }
  __syncthreads();
  const float* W = by == 0 ? Wk : by == 1 ? Wq : by == 2 ? Wv : scw;
  const int bb = g0 >> 8, t0l = g0 & 255;
  const int n0 = wv * 32 + lm, n1 = n0 + 16;
  floatx4 a0 = {0.f,0.f,0.f,0.f}, a1 = {0.f,0.f,0.f,0.f};
#pragma unroll
  for (int kc = 0; kc < 4; kc++) {
    short8 a  = *(const short8*)&xs[lm][kc * 32 + quad * 8];
    short8 bA = ldwfrag(W + (size_t)n0 * 128 + kc * 32 + quad * 8);
    short8 bB = ldwfrag(W + (size_t)n1 * 128 + kc * 32 + quad * 8);
    a0 = MFMA16(a, bA, a0);
    a1 = MFMA16(a, bB, a1);
  }
  proj_epilogue(by, g0, bb, t0l, n0, n1, quad, a0, a1,
                Kb1, Kt1, Qb1, Vt1, skip1, scb);
}

// =========================================================== FF + unmap -> y (128 blocks)
__global__ __launch_bounds__(256) void ffu_kernel(
    const unsigned short* __restrict__ attnb, const unsigned short* __restrict__ skipb,
    const float* __restrict__ w1, const float* __restrict__ b1,
    const float* __restrict__ w2, const float* __restrict__ b2,
    const float* __restrict__ unw, const float* __restrict__ unb,
    float* __restrict__ yout) {
  __shared__ unsigned short xa[16][136];
  __shared__ unsigned short hs[16][136];
  const int tid = threadIdx.x, g0 = blockIdx.x * 16;
  const int lane = tid & 63, wv = tid >> 6, lm = lane & 15, quad = lane >> 4;
  const int n0 = wv * 32 + lm, n1 = n0 + 16;

  short8 w1A[4], w1B[4], w2A[4], w2B[4];
#pragma unroll
  for (int kc = 0; kc < 4; kc++) {
    w1A[kc] = ldwfrag(w1 + (size_t)n0 * 128 + kc * 32 + quad * 8);
    w1B[kc] = ldwfrag(w1 + (size_t)n1 * 128 + kc * 32 + quad * 8);
    w2A[kc] = ldwfrag(w2 + (size_t)n0 * 128 + kc * 32 + quad * 8);
    w2B[kc] = ldwfrag(w2 + (size_t)n1 * 128 + kc * 32 + quad * 8);
  }
  float bi10 = b1[n0], bi11 = b1[n1], bi20 = b2[n0], bi21 = b2[n1];
  float sk0[4], sk1[4];
#pragma unroll
  for (int j = 0; j < 4; j++) {
    sk0[j] = bf2f(skipb[(size_t)(g0 + quad * 4 + j) * 128 + n0]);
    sk1[j] = bf2f(skipb[(size_t)(g0 + quad * 4 + j) * 128 + n1]);
  }
  { int r = tid >> 4, c = (tid & 15) * 8;
    *(short8*)&xa[r][c] = *(const short8*)(attnb + (size_t)(g0 + r) * 128 + c); }
  __syncthreads();

  { floatx4 a0 = {0.f,0.f,0.f,0.f}, a1 = {0.f,0.f,0.f,0.f};
#pragma unroll
    for (int kc = 0; kc < 4; kc++) {
      short8 a = *(const short8*)&xa[lm][kc * 32 + quad * 8];
      a0 = MFMA16(a, w1A[kc], a0);
      a1 = MFMA16(a, w1B[kc], a1);
    }
#pragma unroll
    for (int j = 0; j < 4; j++) {
      int row = quad * 4 + j;
      hs[row][n0] = f2bf(fmaxf(a0[j] + bi10, 0.f));
      hs[row][n1] = f2bf(fmaxf(a1[j] + bi11, 0.f));
    } }
  __syncthreads();
  // unmap weight frags (issue while FF2 runs)
  short8 uA[4], uB[4];
#pragma unroll
  for (int kc = 0; kc < 4; kc++) {
    uA[kc] = ldwfrag(unw + (size_t)n0 * 128 + kc * 32 + quad * 8);
    uB[kc] = ldwfrag(unw + (size_t)n1 * 128 + kc * 32 + quad * 8);
  }
  float o0[4], o1[4];
  { floatx4 a0 = {0.f,0.f,0.f,0.f}, a1 = {0.f,0.f,0.f,0.f};
#pragma unroll
    for (int kc = 0; kc < 4; kc++) {
      short8 a = *(const short8*)&hs[lm][kc * 32 + quad * 8];
      a0 = MFMA16(a, w2A[kc], a0);
      a1 = MFMA16(a, w2B[kc], a1);
    }
#pragma unroll
    for (int j = 0; j < 4; j++) {
      o0[j] = fmaxf(a0[j] + bi20, 0.f) + sk0[j];
      o1[j] = fmaxf(a1[j] + bi21, 0.f) + sk1[j];
    } }
  __syncthreads();          // all FF2 hs-reads done
#pragma unroll
  for (int j = 0; j < 4; j++) {
    int row = quad * 4 + j;
    hs[row][n0] = f2bf(o0[j]);
    hs[row][n1] = f2bf(o1[j]);
  }
  __syncthreads();
  { floatx4 a0 = {0.f,0.f,0.f,0.f}, a1 = {0.f,0.f,0.f,0.f};
#pragma unroll
    for (int kc = 0; kc < 4; kc++) {
      short8 a = *(const short8*)&hs[lm][kc * 32 + quad * 8];
      a0 = MFMA16(a, uA[kc], a0);
      a1 = MFMA16(a, uB[kc], a1);
    }
    float u0 = unb[n0], u1 = unb[n1];
#pragma unroll
    for (int j = 0; j < 4; j++) {
      int gg = g0 + quad * 4 + j;
      int bb = gg >> 8, tq = gg & 255;
      yout[(size_t)(tq * Bn + bb) * 128 + n0] = a0[j] + u0;
      yout[(size_t)(tq * Bn + bb) * 128 + n1] = a1[j] + u1;
    } }
}

// ============================================================ launch
extern "C" void kernel_launch(void* const* d_in, const int* in_sizes, int n_in,
                              void* d_out, int out_size, void* d_ws, size_t ws_size,
                              hipStream_t stream) {
  const float* z       = (const float*)d_in[0];
  const float* state   = (const float*)d_in[1];
  const float* Wk      = (const float*)d_in[2];
  const float* Wq      = (const float*)d_in[3];
  const float* Wv      = (const float*)d_in[4];
  const float* ln_w    = (const float*)d_in[5];
  const float* ln_b    = (const float*)d_in[6];
  const float* ff_w1   = (const float*)d_in[7];
  const float* ff_b1   = (const float*)d_in[8];
  const float* ff_w2   = (const float*)d_in[9];
  const float* ff_b2   = (const float*)d_in[10];
  const float* sc_w    = (const float*)d_in[11];
  const float* sc_b    = (const float*)d_in[12];
  const float* unmap_w = (const float*)d_in[13];
  const float* unmap_b = (const float*)d_in[14];

  float* y_out  = (float*)d_out;                      // (T,B,128)
  float* st_out = y_out + (size_t)Tn * Bn * 128;      // (B,SDn)

  const size_t E = 262144;                            // 2048*128
  unsigned short* Kb0  = (unsigned short*)d_ws;
  unsigned short* Qb0  = Kb0 + E;
  unsigned short* Kt0  = Qb0 + E;
  unsigned short* Vt0  = Kt0 + E;
  unsigned short* Kb1  = Vt0 + E;
  unsigned short* Qb1  = Kb1 + E;
  unsigned short* Kt1  = Qb1 + E;
  unsigned short* Vt1  = Kt1 + E;
  unsigned short* skip0 = Vt1 + E;
  unsigned short* skip1 = skip0 + E;
  unsigned short* attnb = skip1 + E;
  unsigned short* xln1  = attnb + E;
  unsigned short* S0t   = xln1 + E;                   // 2 layers * 8 * 16384

  prep_kernel<<<528, 256, 0, stream>>>(
      z, state, Wk, Wq, Wv, sc_w, ln_w, ln_b, sc_b,
      Kb0, Qb0, Kt0, Vt0, skip0, S0t);

  attn_kernel<<<384, 256, 0, stream>>>(
      Kb0, Qb0, Vt0, Kt0, S0t, state, attnb, st_out, 0);

  ffln_kernel<<<128, 256, 0, stream>>>(
      attnb, skip0, ff_w1, ff_b1, ff_w2, ff_b2,
      ln_w + 128, ln_b + 128, xln1);

  proj1_kernel<<<512, 256, 0, stream>>>(
      xln1, Wk + 16384, Wq + 16384, Wv + 16384, sc_w + 16384, sc_b + 128,
      Kb1, Qb1, Kt1, Vt1, skip1);

  attn_kernel<<<384, 256, 0, stream>>>(
      Kb1, Qb1, Vt1, Kt1, S0t + (size_t)8 * 16384, state, attnb, st_out, 1);

  ffu_kernel<<<128, 256, 0, stream>>>(
      attnb, skip1, ff_w1 + 16384, ff_b1 + 128, ff_w2 + 16384, ff_b2 + 128,
      unmap_w, unmap_b, y_out);
}